// Round 6
// baseline (354.700 us; speedup 1.0000x reference)
//
#include <hip/hip_runtime.h>

typedef __bf16 bf16;
typedef __bf16 bf16x8 __attribute__((ext_vector_type(8)));
typedef __bf16 bf16x4 __attribute__((ext_vector_type(4)));
typedef __bf16 bf16x2 __attribute__((ext_vector_type(2)));
typedef float f32x4 __attribute__((ext_vector_type(4)));
typedef float f32x16 __attribute__((ext_vector_type(16)));
typedef int i32x4 __attribute__((ext_vector_type(4)));
typedef int i32x2 __attribute__((ext_vector_type(2)));

#define GLL16(gp, lp)                                                          \
  __builtin_amdgcn_global_load_lds(                                            \
      (const __attribute__((address_space(1))) unsigned int*)(gp),             \
      (__attribute__((address_space(3))) unsigned int*)(lp), 16, 0, 0)

// ------------------------------------------------------- fused fp32->bf16 casts
__global__ __launch_bounds__(256) void cast3_f32_bf16(
    const float* __restrict__ a, bf16* __restrict__ oa, int na4,
    const float* __restrict__ b, bf16* __restrict__ ob, int nb4,
    const float* __restrict__ c, bf16* __restrict__ oc, int nc4) {
  int i = blockIdx.x * blockDim.x + threadIdx.x;
  int stride = gridDim.x * blockDim.x;
  int total = na4 + nb4 + nc4;
  for (; i < total; i += stride) {
    const float4* src;
    bf16x4* dst;
    int j = i;
    if (j < na4) {
      src = (const float4*)a + j; dst = (bf16x4*)oa + j;
    } else if ((j -= na4) < nb4) {
      src = (const float4*)b + j; dst = (bf16x4*)ob + j;
    } else {
      j -= nb4;
      src = (const float4*)c + j; dst = (bf16x4*)oc + j;
    }
    float4 v = *src;
    bf16x4 o;
    o[0] = (bf16)v.x; o[1] = (bf16)v.y; o[2] = (bf16)v.z; o[3] = (bf16)v.w;
    *dst = o;
  }
}

// ---------------------------------------------------------------- GEMM C = A * B^T
// 1D grid + bijective XCD swizzle (grid % 8 == 0): each XCD gets a contiguous
// wg range -> B panel L2-resident per XCD. BM in {128,64}; NBX = n-blocks.
template <int K, int LDC, int BM, int NBX, typename CT>
__global__ __launch_bounds__(256) void gemm_bt(
    const bf16* __restrict__ A, const bf16* __restrict__ B,
    CT* __restrict__ C) {
  __shared__ __align__(16) bf16 As[BM * 64];
  __shared__ __align__(16) bf16 Bs[128 * 64];
  const int tid  = threadIdx.x;
  const int lane = tid & 63;
  const int wave = tid >> 6;
  const int ln15 = lane & 15, quad = lane >> 4;
  const int wm = wave >> 1, wn = wave & 1;
  const int flat = blockIdx.x;
  const int wg = (flat & 7) * (gridDim.x >> 3) + (flat >> 3);
  const int m0 = (wg / NBX) * BM, n0 = (wg % NBX) * 128;
  constexpr int MI = BM / 32;  // 16-row m-frags per wave

  f32x4 acc[MI][4] = {};

  for (int k0 = 0; k0 < K; k0 += 64) {
    __syncthreads();
#pragma unroll
    for (int j = 0; j < BM / 32; ++j) {
      int gbase = j * 256 + wave * 64;
      int g = gbase + lane;
      int r = g >> 3, c = (g & 7) ^ (r & 7);
      GLL16(A + (size_t)(m0 + r) * K + k0 + c * 8, As + (size_t)gbase * 8);
    }
#pragma unroll
    for (int j = 0; j < 4; ++j) {
      int gbase = j * 256 + wave * 64;
      int g = gbase + lane;
      int r = g >> 3, c = (g & 7) ^ (r & 7);
      GLL16(B + (size_t)(n0 + r) * K + k0 + c * 8, Bs + (size_t)gbase * 8);
    }
    __syncthreads();
#pragma unroll
    for (int kk = 0; kk < 2; ++kk) {
      bf16x8 af[MI], bfr[4];
#pragma unroll
      for (int mi = 0; mi < MI; ++mi) {
        int m = wm * (BM / 2) + mi * 16 + ln15;
        int cg = kk * 4 + quad;
        af[mi] = *(const bf16x8*)(As + (m * 8 + (cg ^ (m & 7))) * 8);
      }
#pragma unroll
      for (int ni = 0; ni < 4; ++ni) {
        int n = wn * 64 + ni * 16 + ln15;
        int cg = kk * 4 + quad;
        bfr[ni] = *(const bf16x8*)(Bs + (n * 8 + (cg ^ (n & 7))) * 8);
      }
#pragma unroll
      for (int mi = 0; mi < MI; ++mi)
#pragma unroll
        for (int ni = 0; ni < 4; ++ni)
          acc[mi][ni] = __builtin_amdgcn_mfma_f32_16x16x32_bf16(
              af[mi], bfr[ni], acc[mi][ni], 0, 0, 0);
    }
  }
#pragma unroll
  for (int mi = 0; mi < MI; ++mi)
#pragma unroll
    for (int ni = 0; ni < 4; ++ni)
#pragma unroll
      for (int r = 0; r < 4; ++r) {
        int row = m0 + wm * (BM / 2) + mi * 16 + quad * 4 + r;
        int col = n0 + wn * 64 + ni * 16 + ln15;
        C[(size_t)row * LDC + col] = (CT)acc[mi][ni][r];
      }
}

// ---------------------------------------------------------------- qkv epilogue
// Vectorized (round 15). Also zeroes the flash last-finisher counters (block
// (0,0)) — placed here because this kernel runs after gemm1 consumed wqkv,
// whose dead region hosts the counters.
__global__ __launch_bounds__(256) void qkv_post(
    const bf16* __restrict__ qkv, const float* __restrict__ ve,
    const float* __restrict__ lambdas, bf16* __restrict__ qn,
    bf16* __restrict__ kn, bf16* __restrict__ vt, int* __restrict__ cnt) {
  const int h  = blockIdx.x;
  const int t0 = blockIdx.y * 64;
  const int tid = threadIdx.x;
  const int wave = tid >> 6, lane = tid & 63;
  const int l31 = lane & 31, hl = lane >> 5;
  __shared__ __align__(16) float tile[64][129];

  if (h == 0 && blockIdx.y == 0) cnt[tid] = 0;  // 256 counters

  // ---- q,k: rms + rotary (16 rows per wave, q and k per row)
  const int d0 = 2 * l31 + 64 * hl;
  const int trow0 = t0 + wave * 16;
  float ca0 = 1.f, sa0 = 0.f, ca1 = 1.f, sa1 = 0.f;  // per-row increment
  float c0 = 1.f, s0 = 0.f, c1 = 1.f, s1 = 0.f;      // current row angle
  if (l31 < 16) {
    float a0 = exp2f((float)(2 * l31) * (-10.0f / 31.0f));
    float a1 = exp2f((float)(2 * l31 + 1) * (-10.0f / 31.0f));
    __sincosf(a0, &sa0, &ca0);
    __sincosf(a1, &sa1, &ca1);
    __sincosf((float)trow0 * a0, &s0, &c0);
    __sincosf((float)trow0 * a1, &s1, &c1);
  }

  for (int i = 0; i < 16; ++i) {
    int t = trow0 + i;
    float s0m = hl ? -s0 : s0;
    float s1m = hl ? -s1 : s1;
#pragma unroll
    for (int qk = 0; qk < 2; ++qk) {
      const bf16* row = qkv + (size_t)t * 3072 + qk * 1024 + h * 128;
      bf16x2 xp = *(const bf16x2*)(row + d0);
      float xa = (float)xp[0], xb = (float)xp[1];
      float ss = xa * xa + xb * xb;
#pragma unroll
      for (int m = 1; m < 64; m <<= 1) ss += __shfl_xor(ss, m, 64);
      float rinv = rsqrtf(ss * (1.0f / 128.0f) + 1.1920929e-7f);
      if (qk == 0) rinv *= 0.12f;  // fold ATTN_SCALE into q
      float pa = __shfl_xor(xa, 32, 64);
      float pb = __shfl_xor(xb, 32, 64);
      float ya = (xa * c0 + pa * s0m) * rinv;
      float yb2 = (xb * c1 + pb * s1m) * rinv;
      bf16* orow = (qk == 0 ? qn : kn) + (size_t)t * 1024 + h * 128;
      bf16x2 o; o[0] = (bf16)ya; o[1] = (bf16)yb2;
      *(bf16x2*)(orow + d0) = o;
    }
    float nc0 = c0 * ca0 - s0 * sa0, ns0 = s0 * ca0 + c0 * sa0;
    float nc1 = c1 * ca1 - s1 * sa1, ns1 = s1 * ca1 + c1 * sa1;
    c0 = nc0; s0 = ns0; c1 = nc1; s1 = ns1;
  }

  // ---- v: lambda-mix + transpose to vt[d][T]
  float l0 = lambdas[0], l1 = lambdas[1];
  for (int c = 0; c < 16; ++c) {
    int idx = c * 512 + tid * 2;
    int d = idx & 127, tl = idx >> 7;
    int t = t0 + tl;
    bf16x2 vp = *(const bf16x2*)(qkv + (size_t)t * 3072 + 2048 + h * 128 + d);
    float2 vev = *(const float2*)(ve + (size_t)t * 1024 + h * 128 + d);
    tile[tl][d]     = l0 * (float)vp[0] + l1 * vev.x;
    tile[tl][d + 1] = l0 * (float)vp[1] + l1 * vev.y;
  }
  __syncthreads();
  for (int c = 0; c < 16; ++c) {
    int idx = c * 512 + tid * 2;
    int tl = idx & 63, d = idx >> 6;  // two consecutive t, same d
    bf16x2 o;
    o[0] = (bf16)tile[tl][d];
    o[1] = (bf16)tile[tl + 1][d];
    *(bf16x2*)(vt + ((size_t)(h * 128 + d)) * 4096 + t0 + tl) = o;
  }
}

// ---------------------------------------------------------------- flash attention
// Round 13 core (proven) + round 16: fused last-finisher combine. Both kv-half
// blocks of a (h,qt) write raw partials; the SECOND to finish (device-scope
// atomic counter) re-reads both partials (L2/L3-hot) and writes yb directly.
// attn_combine kernel eliminated; its traffic overlaps flash's tail.
__global__ __launch_bounds__(256, 2) void flash_attn(
    const bf16* __restrict__ qn, const bf16* __restrict__ kn,
    const bf16* __restrict__ vt, float* __restrict__ Op,
    float* __restrict__ ls, int* __restrict__ cnt, bf16* __restrict__ yb) {
  const int id = blockIdx.x;  // 0..511
  const int qt = (id < 256) ? (31 - (id >> 4)) : ((id - 256) >> 4);
  const int sub = id & 15;
  const int h = sub >> 1;
  const int half = sub & 1;
  const int tid = threadIdx.x;
  const int wave = tid >> 6, lane = tid & 63;
  const int l31 = lane & 31, hl = lane >> 5;

  __shared__ __align__(16) bf16 smem[4 * 64 * 128];  // 64 KB: Ks(2x16K)+Vs(2x16K)
  bf16* Ks = smem;                  // [buf][kv][16 gran] ^(kv&15)
  bf16* Vs = smem + 2 * 64 * 128;   // [buf][d][8 gran]  ^(d&7)

  const int nkv = 2 * (qt + 1);
  const int half0 = qt + 1;
  const int kt_begin = half ? half0 : 0;
  const int kt_end = half ? nkv : half0;
  const int niter = kt_end - kt_begin;  // = qt+1 >= 1
  const int pidx = (h * 32 + qt) * 2 + half;

  const int qminw = qt * 128 + wave * 32;  // this wave's lowest q row
  const int qg = qminw + l31;              // this lane's q (B n-dim / C col)

  // Q B-frags (B[k=d][n=q], k=(lane>>5)*8+j): 8 frags cover d=0..127.
  bf16x8 qf[8];
  {
    const bf16* qb = qn + (size_t)qg * 1024 + h * 128 + hl * 8;
#pragma unroll
    for (int f = 0; f < 8; ++f) qf[f] = *(const bf16x8*)(qb + f * 16);
  }

  f32x16 acc_o[4] = {};  // O^T[d=dt*32+..][q 32] for this wave
  float rs = 0.0f;

  auto prefetch = [&](int kt, int buf) {
    const int kv0 = kt * 64;
    bf16* ks = Ks + buf * (64 * 128);
    bf16* vs = Vs + buf * (128 * 64);
#pragma unroll
    for (int jj = 0; jj < 4; ++jj) {  // K tile: 64 rows x 16 granules
      int gbase = jj * 256 + wave * 64;
      int g = gbase + lane;
      int r = g >> 4, c = (g & 15) ^ (r & 15);
      GLL16(kn + (size_t)(kv0 + r) * 1024 + h * 128 + c * 8,
            ks + (size_t)gbase * 8);
    }
#pragma unroll
    for (int jj = 0; jj < 4; ++jj) {  // V^T tile: 128 rows x 8 granules
      int gbase = jj * 256 + wave * 64;
      int g = gbase + lane;
      int d = g >> 3, c = (g & 7) ^ (d & 7);
      GLL16(vt + ((size_t)(h * 128 + d)) * 4096 + kv0 + c * 8,
            vs + (size_t)gbase * 8);
    }
  };

  prefetch(kt_begin, 0);

  for (int it = 0; it < niter; ++it) {
    const int kt = kt_begin + it;
    const int kv0 = kt * 64;
    __syncthreads();  // drains this wave's GLL16s; gates buffer reuse
    if (it + 1 < niter) prefetch(kt + 1, (it + 1) & 1);
    const bf16* ksb = Ks + (it & 1) * (64 * 128);
    const bf16* vsb = Vs + (it & 1) * (128 * 64);

    if (kv0 > qminw + 31) continue;  // wave-uniform: tile entirely above diag

    // ---- S^T = K-tile * Q^T: kv-half chains acc0 (rows 0..31), acc1 (32..63)
    f32x16 acc0 = {}, acc1 = {};
    const int l15 = l31 & 15;
    __builtin_amdgcn_s_setprio(1);
#pragma unroll
    for (int f = 0; f < 8; ++f) {
      bf16x8 a0 = *(const bf16x8*)(
          ksb + (l31 * 16 + ((2 * f + hl) ^ l15)) * 8);
      bf16x8 a1 = *(const bf16x8*)(
          ksb + ((32 + l31) * 16 + ((2 * f + hl) ^ l15)) * 8);
      acc0 = __builtin_amdgcn_mfma_f32_32x32x16_bf16(a0, qf[f], acc0, 0, 0, 0);
      acc1 = __builtin_amdgcn_mfma_f32_32x32x16_bf16(a1, qf[f], acc1, 0, 0, 0);
    }
    __builtin_amdgcn_s_setprio(0);

    // ---- exp + causal mask (C row = (r&3)+8*(r>>2)+4*hl); mask only near diag
    const bool needmask = (kv0 + 63 > qminw);
    float rsp[4] = {0.f, 0.f, 0.f, 0.f};
    if (needmask) {
#pragma unroll
      for (int rr = 0; rr < 16; ++rr) {
        int kvl = (rr & 3) + 8 * (rr >> 2) + 4 * hl;
        float v0 = __expf(acc0[rr]);
        float v1 = __expf(acc1[rr]);
        if (kv0 + kvl > qg) v0 = 0.0f;
        if (kv0 + 32 + kvl > qg) v1 = 0.0f;
        acc0[rr] = v0; acc1[rr] = v1;
        rsp[rr & 3] += v0 + v1;
      }
    } else {
#pragma unroll
      for (int rr = 0; rr < 16; ++rr) {
        float v0 = __expf(acc0[rr]);
        float v1 = __expf(acc1[rr]);
        acc0[rr] = v0; acc1[rr] = v1;
        rsp[rr & 3] += v0 + v1;
      }
    }
    rs += (rsp[0] + rsp[1]) + (rsp[2] + rsp[3]);

    // pack kv-pairs: pkX[g] = (kv base(g)+4hl, +1), base(g)=8*(g>>1)+2*(g&1)
    int pk0[8], pk1[8];
#pragma unroll
    for (int g = 0; g < 8; ++g) {
      bf16x2 t0, t1;
      t0[0] = (bf16)acc0[2 * g]; t0[1] = (bf16)acc0[2 * g + 1];
      t1[0] = (bf16)acc1[2 * g]; t1[1] = (bf16)acc1[2 * g + 1];
      pk0[g] = __builtin_bit_cast(int, t0);
      pk1[g] = __builtin_bit_cast(int, t1);
    }

    // ---- in-register transpose to PV B-frags; chunk cc covers kv [cc*16,+16)
    bf16x8 pf[4];
#if __has_builtin(__builtin_amdgcn_permlane32_swap)
#pragma unroll
    for (int cc = 0; cc < 4; ++cc) {
      int s0 = (cc < 2) ? pk0[(cc & 1) * 4 + 0] : pk1[(cc & 1) * 4 + 0];
      int s1 = (cc < 2) ? pk0[(cc & 1) * 4 + 1] : pk1[(cc & 1) * 4 + 1];
      int s2 = (cc < 2) ? pk0[(cc & 1) * 4 + 2] : pk1[(cc & 1) * 4 + 2];
      int s3 = (cc < 2) ? pk0[(cc & 1) * 4 + 3] : pk1[(cc & 1) * 4 + 3];
      i32x2 r02 = __builtin_amdgcn_permlane32_swap(s0, s2, false, false);
      i32x2 r13 = __builtin_amdgcn_permlane32_swap(s1, s3, false, false);
      i32x4 dv;
      dv[0] = r02[0];  // t=0: src half 0
      dv[1] = r13[0];  // t=1: src half 0
      dv[2] = r02[1];  // t=2: src half 1
      dv[3] = r13[1];  // t=3: src half 1
      pf[cc] = __builtin_bit_cast(bf16x8, dv);
    }
#else
#pragma unroll
    for (int cc = 0; cc < 4; ++cc) {
      int s0 = (cc < 2) ? pk0[(cc & 1) * 4 + 0] : pk1[(cc & 1) * 4 + 0];
      int s1 = (cc < 2) ? pk0[(cc & 1) * 4 + 1] : pk1[(cc & 1) * 4 + 1];
      int s2 = (cc < 2) ? pk0[(cc & 1) * 4 + 2] : pk1[(cc & 1) * 4 + 2];
      int s3 = (cc < 2) ? pk0[(cc & 1) * 4 + 3] : pk1[(cc & 1) * 4 + 3];
      int sh0 = __shfl_xor(s0, 32, 64);
      int sh1 = __shfl_xor(s1, 32, 64);
      int sh2 = __shfl_xor(s2, 32, 64);
      int sh3 = __shfl_xor(s3, 32, 64);
      int own0 = hl ? s2 : s0;
      int own1 = hl ? s3 : s1;
      int par0 = hl ? sh2 : sh0;
      int par1 = hl ? sh3 : sh1;
      i32x4 dv;
      dv[0] = hl ? par0 : own0;
      dv[1] = hl ? par1 : own1;
      dv[2] = hl ? own0 : par0;
      dv[3] = hl ? own1 : par1;
      pf[cc] = __builtin_bit_cast(bf16x8, dv);
    }
#endif

    // ---- O^T[d][q] += V^T-tile * P^T; V kv-granule = 2*cc + hl
    __builtin_amdgcn_s_setprio(1);
#pragma unroll
    for (int dt = 0; dt < 4; ++dt) {
      int vrow = dt * 32 + l31;
#pragma unroll
      for (int cc = 0; cc < 4; ++cc) {
        bf16x8 a = *(const bf16x8*)(
            vsb + (vrow * 8 + ((2 * cc + hl) ^ (vrow & 7))) * 8);
        acc_o[dt] =
            __builtin_amdgcn_mfma_f32_32x32x16_bf16(a, pf[cc], acc_o[dt], 0, 0, 0);
      }
    }
    __builtin_amdgcn_s_setprio(0);
  }

  // ---- epilogue: each wave owns q rows [wave*32, +32) — direct float4 stores
  rs += __shfl_xor(rs, 32, 64);
  if (hl == 0) ls[pidx * 128 + wave * 32 + l31] = rs;
  float* opb = Op + (size_t)pidx * 16384 + (size_t)(wave * 32 + l31) * 128;
#pragma unroll
  for (int dt = 0; dt < 4; ++dt)
#pragma unroll
    for (int rg = 0; rg < 4; ++rg) {
      float4 o;
      o.x = acc_o[dt][rg * 4 + 0];
      o.y = acc_o[dt][rg * 4 + 1];
      o.z = acc_o[dt][rg * 4 + 2];
      o.w = acc_o[dt][rg * 4 + 3];
      int d0 = dt * 32 + 4 * hl + 8 * rg;
      *(float4*)(opb + d0) = o;
    }

  // ---- fused combine: second finisher of (h,qt) merges both partials -> yb
  __threadfence();  // release partial O / l stores (device scope)
  __shared__ int lastflag;
  if (tid == 0) lastflag = (atomicAdd(&cnt[pidx >> 1], 1) == 1);
  __syncthreads();
  if (!lastflag) return;
  __threadfence();  // acquire other block's partials
  const int pb = pidx & ~1;
  const float* op0 = Op + (size_t)pb * 16384;
  const float* op1 = Op + (size_t)(pb + 1) * 16384;
#pragma unroll
  for (int c = 0; c < 16; ++c) {
    int idx = c * 256 + tid;
    int ql = idx >> 5;
    int d4 = (idx & 31) * 4;
    float4 o0 = *(const float4*)(op0 + ql * 128 + d4);
    float4 o1 = *(const float4*)(op1 + ql * 128 + d4);
    float inv = 1.0f / (ls[pb * 128 + ql] + ls[(pb + 1) * 128 + ql]);
    bf16x4 ov;
    ov[0] = (bf16)((o0.x + o1.x) * inv);
    ov[1] = (bf16)((o0.y + o1.y) * inv);
    ov[2] = (bf16)((o0.z + o1.z) * inv);
    ov[3] = (bf16)((o0.w + o1.w) * inv);
    *(bf16x4*)(yb + (size_t)(qt * 128 + ql) * 1024 + h * 128 + d4) = ov;
  }
}

// ---------------------------------------------------------------- launch
extern "C" void kernel_launch(void* const* d_in, const int* in_sizes, int n_in,
                              void* d_out, int out_size, void* d_ws,
                              size_t ws_size, hipStream_t stream) {
  const float* x       = (const float*)d_in[0];  // [1,4096,1024]
  const float* ve      = (const float*)d_in[1];  // [1,4096,1024]
  const float* qkv_w   = (const float*)d_in[2];  // [3,1024,1024]
  const float* lambdas = (const float*)d_in[3];  // [2]
  const float* c_proj  = (const float*)d_in[4];  // [1024,1024]
  float* out = (float*)d_out;                    // [1,4096,1024] fp32

  char* ws = (char*)d_ws;
  bf16* qkv   = (bf16*)ws;                    // 24 MiB (dead after qkv_post)
  bf16* xbf   = (bf16*)(ws + 25165824);       // 8 MiB  (dead after gemm1)
  bf16* wqkv  = (bf16*)(ws + 33554432);       // 6 MiB  (dead after gemm1)
  bf16* wproj = (bf16*)(ws + 39845888);       // 2 MiB
  bf16* qn    = (bf16*)(ws + 41943040);       // 8 MiB
  bf16* kn    = (bf16*)(ws + 50331648);       // 8 MiB
  bf16* vt    = (bf16*)(ws + 58720256);       // 8 MiB  [H][128][T]
  bf16* yb    = (bf16*)(ws + 67108864);       // 8 MiB
  // flash partials ALIAS dead regions (stream-ordered: flash runs after
  // gemm1/qkv_post consumed them):
  float* Op  = (float*)ws;                    // 32 MiB  [512][128][128] f32
  float* lsw = (float*)(ws + 33554432);       // 256 KiB [512][128] f32
  int*   cnt = (int*)(ws + 33816576);         // 1 KiB   [256] (dead-wqkv area)

  cast3_f32_bf16<<<2048, 256, 0, stream>>>(x, xbf, 4194304 / 4, qkv_w, wqkv,
                                           3145728 / 4, c_proj, wproj,
                                           1048576 / 4);

  gemm_bt<1024, 3072, 128, 24, bf16><<<768, 256, 0, stream>>>(xbf, wqkv, qkv);

  qkv_post<<<dim3(8, 64), 256, 0, stream>>>(qkv, ve, lambdas, qn, kn, vt, cnt);

  flash_attn<<<512, 256, 0, stream>>>(qn, kn, vt, Op, lsw, cnt, yb);

  gemm_bt<1024, 1024, 64, 8, float><<<512, 256, 0, stream>>>(yb, wproj, out);
}

// Round 7
// 239.581 us; speedup vs baseline: 1.4805x; 1.4805x over previous
//
#include <hip/hip_runtime.h>

typedef __bf16 bf16;
typedef __bf16 bf16x8 __attribute__((ext_vector_type(8)));
typedef __bf16 bf16x4 __attribute__((ext_vector_type(4)));
typedef __bf16 bf16x2 __attribute__((ext_vector_type(2)));
typedef float f32x4 __attribute__((ext_vector_type(4)));
typedef float f32x16 __attribute__((ext_vector_type(16)));
typedef int i32x4 __attribute__((ext_vector_type(4)));
typedef int i32x2 __attribute__((ext_vector_type(2)));

#define GLL16(gp, lp)                                                          \
  __builtin_amdgcn_global_load_lds(                                            \
      (const __attribute__((address_space(1))) unsigned int*)(gp),             \
      (__attribute__((address_space(3))) unsigned int*)(lp), 16, 0, 0)

// ------------------------------------------------------- fused fp32->bf16 casts
__global__ __launch_bounds__(256) void cast3_f32_bf16(
    const float* __restrict__ a, bf16* __restrict__ oa, int na4,
    const float* __restrict__ b, bf16* __restrict__ ob, int nb4,
    const float* __restrict__ c, bf16* __restrict__ oc, int nc4) {
  int i = blockIdx.x * blockDim.x + threadIdx.x;
  int stride = gridDim.x * blockDim.x;
  int total = na4 + nb4 + nc4;
  for (; i < total; i += stride) {
    const float4* src;
    bf16x4* dst;
    int j = i;
    if (j < na4) {
      src = (const float4*)a + j; dst = (bf16x4*)oa + j;
    } else if ((j -= na4) < nb4) {
      src = (const float4*)b + j; dst = (bf16x4*)ob + j;
    } else {
      j -= nb4;
      src = (const float4*)c + j; dst = (bf16x4*)oc + j;
    }
    float4 v = *src;
    bf16x4 o;
    o[0] = (bf16)v.x; o[1] = (bf16)v.y; o[2] = (bf16)v.z; o[3] = (bf16)v.w;
    *dst = o;
  }
}

// ---------------------------------------------------------------- GEMM C = A * B^T
// 1D grid + bijective XCD swizzle (grid % 8 == 0). Used for gemm1 (qkv).
template <int K, int LDC, int BM, int NBX, typename CT>
__global__ __launch_bounds__(256) void gemm_bt(
    const bf16* __restrict__ A, const bf16* __restrict__ B,
    CT* __restrict__ C) {
  __shared__ __align__(16) bf16 As[BM * 64];
  __shared__ __align__(16) bf16 Bs[128 * 64];
  const int tid  = threadIdx.x;
  const int lane = tid & 63;
  const int wave = tid >> 6;
  const int ln15 = lane & 15, quad = lane >> 4;
  const int wm = wave >> 1, wn = wave & 1;
  const int flat = blockIdx.x;
  const int wg = (flat & 7) * (gridDim.x >> 3) + (flat >> 3);
  const int m0 = (wg / NBX) * BM, n0 = (wg % NBX) * 128;
  constexpr int MI = BM / 32;  // 16-row m-frags per wave

  f32x4 acc[MI][4] = {};

  for (int k0 = 0; k0 < K; k0 += 64) {
    __syncthreads();
#pragma unroll
    for (int j = 0; j < BM / 32; ++j) {
      int gbase = j * 256 + wave * 64;
      int g = gbase + lane;
      int r = g >> 3, c = (g & 7) ^ (r & 7);
      GLL16(A + (size_t)(m0 + r) * K + k0 + c * 8, As + (size_t)gbase * 8);
    }
#pragma unroll
    for (int j = 0; j < 4; ++j) {
      int gbase = j * 256 + wave * 64;
      int g = gbase + lane;
      int r = g >> 3, c = (g & 7) ^ (r & 7);
      GLL16(B + (size_t)(n0 + r) * K + k0 + c * 8, Bs + (size_t)gbase * 8);
    }
    __syncthreads();
#pragma unroll
    for (int kk = 0; kk < 2; ++kk) {
      bf16x8 af[MI], bfr[4];
#pragma unroll
      for (int mi = 0; mi < MI; ++mi) {
        int m = wm * (BM / 2) + mi * 16 + ln15;
        int cg = kk * 4 + quad;
        af[mi] = *(const bf16x8*)(As + (m * 8 + (cg ^ (m & 7))) * 8);
      }
#pragma unroll
      for (int ni = 0; ni < 4; ++ni) {
        int n = wn * 64 + ni * 16 + ln15;
        int cg = kk * 4 + quad;
        bfr[ni] = *(const bf16x8*)(Bs + (n * 8 + (cg ^ (n & 7))) * 8);
      }
#pragma unroll
      for (int mi = 0; mi < MI; ++mi)
#pragma unroll
        for (int ni = 0; ni < 4; ++ni)
          acc[mi][ni] = __builtin_amdgcn_mfma_f32_16x16x32_bf16(
              af[mi], bfr[ni], acc[mi][ni], 0, 0, 0);
    }
  }
#pragma unroll
  for (int mi = 0; mi < MI; ++mi)
#pragma unroll
    for (int ni = 0; ni < 4; ++ni)
#pragma unroll
      for (int r = 0; r < 4; ++r) {
        int row = m0 + wm * (BM / 2) + mi * 16 + quad * 4 + r;
        int col = n0 + wn * 64 + ni * 16 + ln15;
        C[(size_t)row * LDC + col] = (CT)acc[mi][ni][r];
      }
}

// ------------------------------------------- proj GEMM with fused attn-combine
// out = ((Op[pb] + Op[pb+1]) / (l0+l1)) * wproj^T. A-tile is reg-staged: load
// both raw f32 partials, combine, cvt bf16, ds_write to the SAME swizzled LDS
// slot the GLL16 path used (source-swizzle == dest-linear identity). B stays
// GLL16. No fences: flash->gemm ordering is the kernel boundary.
__global__ __launch_bounds__(256) void gemm_proj(
    const float* __restrict__ Op, const float* __restrict__ ls,
    const bf16* __restrict__ B, float* __restrict__ C) {
  __shared__ __align__(16) bf16 As[64 * 64];
  __shared__ __align__(16) bf16 Bs[128 * 64];
  const int tid  = threadIdx.x;
  const int lane = tid & 63;
  const int wave = tid >> 6;
  const int ln15 = lane & 15, quad = lane >> 4;
  const int wm = wave >> 1, wn = wave & 1;
  const int flat = blockIdx.x;
  const int wg = (flat & 7) * (gridDim.x >> 3) + (flat >> 3);
  const int m0 = (wg >> 3) * 64, n0 = (wg & 7) * 128;

  f32x4 acc[2][4] = {};

  for (int k0 = 0; k0 < 1024; k0 += 64) {
    __syncthreads();
    const int h = k0 >> 7;          // head of this k-tile
    const int dbase = k0 & 127;     // d-offset within head
#pragma unroll
    for (int j = 0; j < 2; ++j) {
      int g = j * 256 + tid;        // 0..511
      int r = g >> 3, c = (g & 7) ^ (r & 7);
      int t = m0 + r;
      int qt = t >> 7, ql = t & 127;
      int pb = (h * 32 + qt) * 2;
      const float* p0 = Op + (size_t)pb * 16384 + ql * 128 + dbase + c * 8;
      const float* p1 = p0 + 16384;
      float4 a0 = *(const float4*)p0;
      float4 b0 = *(const float4*)(p0 + 4);
      float4 a1 = *(const float4*)p1;
      float4 b1 = *(const float4*)(p1 + 4);
      float inv = 1.0f / (ls[pb * 128 + ql] + ls[(pb + 1) * 128 + ql]);
      bf16x8 v;
      v[0] = (bf16)((a0.x + a1.x) * inv);
      v[1] = (bf16)((a0.y + a1.y) * inv);
      v[2] = (bf16)((a0.z + a1.z) * inv);
      v[3] = (bf16)((a0.w + a1.w) * inv);
      v[4] = (bf16)((b0.x + b1.x) * inv);
      v[5] = (bf16)((b0.y + b1.y) * inv);
      v[6] = (bf16)((b0.z + b1.z) * inv);
      v[7] = (bf16)((b0.w + b1.w) * inv);
      *(bf16x8*)(As + (size_t)g * 8) = v;
    }
#pragma unroll
    for (int j = 0; j < 4; ++j) {
      int gbase = j * 256 + wave * 64;
      int g = gbase + lane;
      int r = g >> 3, c = (g & 7) ^ (r & 7);
      GLL16(B + (size_t)(n0 + r) * 1024 + k0 + c * 8, Bs + (size_t)gbase * 8);
    }
    __syncthreads();
#pragma unroll
    for (int kk = 0; kk < 2; ++kk) {
      bf16x8 af[2], bfr[4];
#pragma unroll
      for (int mi = 0; mi < 2; ++mi) {
        int m = wm * 32 + mi * 16 + ln15;
        int cg = kk * 4 + quad;
        af[mi] = *(const bf16x8*)(As + (m * 8 + (cg ^ (m & 7))) * 8);
      }
#pragma unroll
      for (int ni = 0; ni < 4; ++ni) {
        int n = wn * 64 + ni * 16 + ln15;
        int cg = kk * 4 + quad;
        bfr[ni] = *(const bf16x8*)(Bs + (n * 8 + (cg ^ (n & 7))) * 8);
      }
#pragma unroll
      for (int mi = 0; mi < 2; ++mi)
#pragma unroll
        for (int ni = 0; ni < 4; ++ni)
          acc[mi][ni] = __builtin_amdgcn_mfma_f32_16x16x32_bf16(
              af[mi], bfr[ni], acc[mi][ni], 0, 0, 0);
    }
  }
#pragma unroll
  for (int mi = 0; mi < 2; ++mi)
#pragma unroll
    for (int ni = 0; ni < 4; ++ni)
#pragma unroll
      for (int r = 0; r < 4; ++r) {
        int row = m0 + wm * 32 + mi * 16 + quad * 4 + r;
        int col = n0 + wn * 64 + ni * 16 + ln15;
        C[(size_t)row * 1024 + col] = acc[mi][ni][r];
      }
}

// ---------------------------------------------------------------- qkv epilogue
__global__ __launch_bounds__(256) void qkv_post(
    const bf16* __restrict__ qkv, const float* __restrict__ ve,
    const float* __restrict__ lambdas, bf16* __restrict__ qn,
    bf16* __restrict__ kn, bf16* __restrict__ vt) {
  const int h  = blockIdx.x;
  const int t0 = blockIdx.y * 64;
  const int tid = threadIdx.x;
  const int wave = tid >> 6, lane = tid & 63;
  const int l31 = lane & 31, hl = lane >> 5;
  __shared__ __align__(16) float tile[64][129];

  // ---- q,k: rms + rotary (16 rows per wave, q and k per row)
  const int d0 = 2 * l31 + 64 * hl;
  const int trow0 = t0 + wave * 16;
  float ca0 = 1.f, sa0 = 0.f, ca1 = 1.f, sa1 = 0.f;  // per-row increment
  float c0 = 1.f, s0 = 0.f, c1 = 1.f, s1 = 0.f;      // current row angle
  if (l31 < 16) {
    float a0 = exp2f((float)(2 * l31) * (-10.0f / 31.0f));
    float a1 = exp2f((float)(2 * l31 + 1) * (-10.0f / 31.0f));
    __sincosf(a0, &sa0, &ca0);
    __sincosf(a1, &sa1, &ca1);
    __sincosf((float)trow0 * a0, &s0, &c0);
    __sincosf((float)trow0 * a1, &s1, &c1);
  }

  for (int i = 0; i < 16; ++i) {
    int t = trow0 + i;
    float s0m = hl ? -s0 : s0;
    float s1m = hl ? -s1 : s1;
#pragma unroll
    for (int qk = 0; qk < 2; ++qk) {
      const bf16* row = qkv + (size_t)t * 3072 + qk * 1024 + h * 128;
      bf16x2 xp = *(const bf16x2*)(row + d0);
      float xa = (float)xp[0], xb = (float)xp[1];
      float ss = xa * xa + xb * xb;
#pragma unroll
      for (int m = 1; m < 64; m <<= 1) ss += __shfl_xor(ss, m, 64);
      float rinv = rsqrtf(ss * (1.0f / 128.0f) + 1.1920929e-7f);
      if (qk == 0) rinv *= 0.12f;  // fold ATTN_SCALE into q
      float pa = __shfl_xor(xa, 32, 64);
      float pb = __shfl_xor(xb, 32, 64);
      float ya = (xa * c0 + pa * s0m) * rinv;
      float yb2 = (xb * c1 + pb * s1m) * rinv;
      bf16* orow = (qk == 0 ? qn : kn) + (size_t)t * 1024 + h * 128;
      bf16x2 o; o[0] = (bf16)ya; o[1] = (bf16)yb2;
      *(bf16x2*)(orow + d0) = o;
    }
    float nc0 = c0 * ca0 - s0 * sa0, ns0 = s0 * ca0 + c0 * sa0;
    float nc1 = c1 * ca1 - s1 * sa1, ns1 = s1 * ca1 + c1 * sa1;
    c0 = nc0; s0 = ns0; c1 = nc1; s1 = ns1;
  }

  // ---- v: lambda-mix + transpose to vt[d][T]
  float l0 = lambdas[0], l1 = lambdas[1];
  for (int c = 0; c < 16; ++c) {
    int idx = c * 512 + tid * 2;
    int d = idx & 127, tl = idx >> 7;
    int t = t0 + tl;
    bf16x2 vp = *(const bf16x2*)(qkv + (size_t)t * 3072 + 2048 + h * 128 + d);
    float2 vev = *(const float2*)(ve + (size_t)t * 1024 + h * 128 + d);
    tile[tl][d]     = l0 * (float)vp[0] + l1 * vev.x;
    tile[tl][d + 1] = l0 * (float)vp[1] + l1 * vev.y;
  }
  __syncthreads();
  for (int c = 0; c < 16; ++c) {
    int idx = c * 512 + tid * 2;
    int tl = idx & 63, d = idx >> 6;  // two consecutive t, same d
    bf16x2 o;
    o[0] = (bf16)tile[tl][d];
    o[1] = (bf16)tile[tl + 1][d];
    *(bf16x2*)(vt + ((size_t)(h * 128 + d)) * 4096 + t0 + tl) = o;
  }
}

// ---------------------------------------------------------------- flash attention
// Round 13 core (proven 57.4 us): QBLK 128, 4 waves x 32 q-rows, full 64-kv
// tile per iter, single-barrier GLL16-dbuf pipeline, direct per-wave epilogue.
// NO fences/atomics (round-16 lesson: threadfence = L2 invalidate, -3.4x).
__global__ __launch_bounds__(256, 2) void flash_attn(
    const bf16* __restrict__ qn, const bf16* __restrict__ kn,
    const bf16* __restrict__ vt, float* __restrict__ Op,
    float* __restrict__ ls) {
  const int id = blockIdx.x;  // 0..511
  const int qt = (id < 256) ? (31 - (id >> 4)) : ((id - 256) >> 4);
  const int sub = id & 15;
  const int h = sub >> 1;
  const int half = sub & 1;
  const int tid = threadIdx.x;
  const int wave = tid >> 6, lane = tid & 63;
  const int l31 = lane & 31, hl = lane >> 5;

  __shared__ __align__(16) bf16 smem[4 * 64 * 128];  // 64 KB: Ks(2x16K)+Vs(2x16K)
  bf16* Ks = smem;                  // [buf][kv][16 gran] ^(kv&15)
  bf16* Vs = smem + 2 * 64 * 128;   // [buf][d][8 gran]  ^(d&7)

  const int nkv = 2 * (qt + 1);
  const int half0 = qt + 1;
  const int kt_begin = half ? half0 : 0;
  const int kt_end = half ? nkv : half0;
  const int niter = kt_end - kt_begin;  // = qt+1 >= 1
  const int pidx = (h * 32 + qt) * 2 + half;

  const int qminw = qt * 128 + wave * 32;  // this wave's lowest q row
  const int qg = qminw + l31;              // this lane's q (B n-dim / C col)

  // Q B-frags (B[k=d][n=q], k=(lane>>5)*8+j): 8 frags cover d=0..127.
  bf16x8 qf[8];
  {
    const bf16* qb = qn + (size_t)qg * 1024 + h * 128 + hl * 8;
#pragma unroll
    for (int f = 0; f < 8; ++f) qf[f] = *(const bf16x8*)(qb + f * 16);
  }

  f32x16 acc_o[4] = {};  // O^T[d=dt*32+..][q 32] for this wave
  float rs = 0.0f;

  auto prefetch = [&](int kt, int buf) {
    const int kv0 = kt * 64;
    bf16* ks = Ks + buf * (64 * 128);
    bf16* vs = Vs + buf * (128 * 64);
#pragma unroll
    for (int jj = 0; jj < 4; ++jj) {  // K tile: 64 rows x 16 granules
      int gbase = jj * 256 + wave * 64;
      int g = gbase + lane;
      int r = g >> 4, c = (g & 15) ^ (r & 15);
      GLL16(kn + (size_t)(kv0 + r) * 1024 + h * 128 + c * 8,
            ks + (size_t)gbase * 8);
    }
#pragma unroll
    for (int jj = 0; jj < 4; ++jj) {  // V^T tile: 128 rows x 8 granules
      int gbase = jj * 256 + wave * 64;
      int g = gbase + lane;
      int d = g >> 3, c = (g & 7) ^ (d & 7);
      GLL16(vt + ((size_t)(h * 128 + d)) * 4096 + kv0 + c * 8,
            vs + (size_t)gbase * 8);
    }
  };

  prefetch(kt_begin, 0);

  for (int it = 0; it < niter; ++it) {
    const int kt = kt_begin + it;
    const int kv0 = kt * 64;
    __syncthreads();  // drains this wave's GLL16s; gates buffer reuse
    if (it + 1 < niter) prefetch(kt + 1, (it + 1) & 1);
    const bf16* ksb = Ks + (it & 1) * (64 * 128);
    const bf16* vsb = Vs + (it & 1) * (128 * 64);

    if (kv0 > qminw + 31) continue;  // wave-uniform: tile entirely above diag

    // ---- S^T = K-tile * Q^T: kv-half chains acc0 (rows 0..31), acc1 (32..63)
    f32x16 acc0 = {}, acc1 = {};
    const int l15 = l31 & 15;
    __builtin_amdgcn_s_setprio(1);
#pragma unroll
    for (int f = 0; f < 8; ++f) {
      bf16x8 a0 = *(const bf16x8*)(
          ksb + (l31 * 16 + ((2 * f + hl) ^ l15)) * 8);
      bf16x8 a1 = *(const bf16x8*)(
          ksb + ((32 + l31) * 16 + ((2 * f + hl) ^ l15)) * 8);
      acc0 = __builtin_amdgcn_mfma_f32_32x32x16_bf16(a0, qf[f], acc0, 0, 0, 0);
      acc1 = __builtin_amdgcn_mfma_f32_32x32x16_bf16(a1, qf[f], acc1, 0, 0, 0);
    }
    __builtin_amdgcn_s_setprio(0);

    // ---- exp + causal mask (C row = (r&3)+8*(r>>2)+4*hl); mask only near diag
    const bool needmask = (kv0 + 63 > qminw);
    float rsp[4] = {0.f, 0.f, 0.f, 0.f};
    if (needmask) {
#pragma unroll
      for (int rr = 0; rr < 16; ++rr) {
        int kvl = (rr & 3) + 8 * (rr >> 2) + 4 * hl;
        float v0 = __expf(acc0[rr]);
        float v1 = __expf(acc1[rr]);
        if (kv0 + kvl > qg) v0 = 0.0f;
        if (kv0 + 32 + kvl > qg) v1 = 0.0f;
        acc0[rr] = v0; acc1[rr] = v1;
        rsp[rr & 3] += v0 + v1;
      }
    } else {
#pragma unroll
      for (int rr = 0; rr < 16; ++rr) {
        float v0 = __expf(acc0[rr]);
        float v1 = __expf(acc1[rr]);
        acc0[rr] = v0; acc1[rr] = v1;
        rsp[rr & 3] += v0 + v1;
      }
    }
    rs += (rsp[0] + rsp[1]) + (rsp[2] + rsp[3]);

    // pack kv-pairs: pkX[g] = (kv base(g)+4hl, +1), base(g)=8*(g>>1)+2*(g&1)
    int pk0[8], pk1[8];
#pragma unroll
    for (int g = 0; g < 8; ++g) {
      bf16x2 t0, t1;
      t0[0] = (bf16)acc0[2 * g]; t0[1] = (bf16)acc0[2 * g + 1];
      t1[0] = (bf16)acc1[2 * g]; t1[1] = (bf16)acc1[2 * g + 1];
      pk0[g] = __builtin_bit_cast(int, t0);
      pk1[g] = __builtin_bit_cast(int, t1);
    }

    // ---- in-register transpose to PV B-frags; chunk cc covers kv [cc*16,+16)
    bf16x8 pf[4];
#if __has_builtin(__builtin_amdgcn_permlane32_swap)
#pragma unroll
    for (int cc = 0; cc < 4; ++cc) {
      int s0 = (cc < 2) ? pk0[(cc & 1) * 4 + 0] : pk1[(cc & 1) * 4 + 0];
      int s1 = (cc < 2) ? pk0[(cc & 1) * 4 + 1] : pk1[(cc & 1) * 4 + 1];
      int s2 = (cc < 2) ? pk0[(cc & 1) * 4 + 2] : pk1[(cc & 1) * 4 + 2];
      int s3 = (cc < 2) ? pk0[(cc & 1) * 4 + 3] : pk1[(cc & 1) * 4 + 3];
      i32x2 r02 = __builtin_amdgcn_permlane32_swap(s0, s2, false, false);
      i32x2 r13 = __builtin_amdgcn_permlane32_swap(s1, s3, false, false);
      i32x4 dv;
      dv[0] = r02[0];  // t=0: src half 0
      dv[1] = r13[0];  // t=1: src half 0
      dv[2] = r02[1];  // t=2: src half 1
      dv[3] = r13[1];  // t=3: src half 1
      pf[cc] = __builtin_bit_cast(bf16x8, dv);
    }
#else
#pragma unroll
    for (int cc = 0; cc < 4; ++cc) {
      int s0 = (cc < 2) ? pk0[(cc & 1) * 4 + 0] : pk1[(cc & 1) * 4 + 0];
      int s1 = (cc < 2) ? pk0[(cc & 1) * 4 + 1] : pk1[(cc & 1) * 4 + 1];
      int s2 = (cc < 2) ? pk0[(cc & 1) * 4 + 2] : pk1[(cc & 1) * 4 + 2];
      int s3 = (cc < 2) ? pk0[(cc & 1) * 4 + 3] : pk1[(cc & 1) * 4 + 3];
      int sh0 = __shfl_xor(s0, 32, 64);
      int sh1 = __shfl_xor(s1, 32, 64);
      int sh2 = __shfl_xor(s2, 32, 64);
      int sh3 = __shfl_xor(s3, 32, 64);
      int own0 = hl ? s2 : s0;
      int own1 = hl ? s3 : s1;
      int par0 = hl ? sh2 : sh0;
      int par1 = hl ? sh3 : sh1;
      i32x4 dv;
      dv[0] = hl ? par0 : own0;
      dv[1] = hl ? par1 : own1;
      dv[2] = hl ? own0 : par0;
      dv[3] = hl ? own1 : par1;
      pf[cc] = __builtin_bit_cast(bf16x8, dv);
    }
#endif

    // ---- O^T[d][q] += V^T-tile * P^T; V kv-granule = 2*cc + hl
    __builtin_amdgcn_s_setprio(1);
#pragma unroll
    for (int dt = 0; dt < 4; ++dt) {
      int vrow = dt * 32 + l31;
#pragma unroll
      for (int cc = 0; cc < 4; ++cc) {
        bf16x8 a = *(const bf16x8*)(
            vsb + (vrow * 8 + ((2 * cc + hl) ^ (vrow & 7))) * 8);
        acc_o[dt] =
            __builtin_amdgcn_mfma_f32_32x32x16_bf16(a, pf[cc], acc_o[dt], 0, 0, 0);
      }
    }
    __builtin_amdgcn_s_setprio(0);
  }

  // ---- epilogue: each wave owns q rows [wave*32, +32) — direct float4 stores
  rs += __shfl_xor(rs, 32, 64);
  if (hl == 0) ls[pidx * 128 + wave * 32 + l31] = rs;
  float* opb = Op + (size_t)pidx * 16384 + (size_t)(wave * 32 + l31) * 128;
#pragma unroll
  for (int dt = 0; dt < 4; ++dt)
#pragma unroll
    for (int rg = 0; rg < 4; ++rg) {
      float4 o;
      o.x = acc_o[dt][rg * 4 + 0];
      o.y = acc_o[dt][rg * 4 + 1];
      o.z = acc_o[dt][rg * 4 + 2];
      o.w = acc_o[dt][rg * 4 + 3];
      int d0 = dt * 32 + 4 * hl + 8 * rg;
      *(float4*)(opb + d0) = o;
    }
}

// ---------------------------------------------------------------- launch
extern "C" void kernel_launch(void* const* d_in, const int* in_sizes, int n_in,
                              void* d_out, int out_size, void* d_ws,
                              size_t ws_size, hipStream_t stream) {
  const float* x       = (const float*)d_in[0];  // [1,4096,1024]
  const float* ve      = (const float*)d_in[1];  // [1,4096,1024]
  const float* qkv_w   = (const float*)d_in[2];  // [3,1024,1024]
  const float* lambdas = (const float*)d_in[3];  // [2]
  const float* c_proj  = (const float*)d_in[4];  // [1024,1024]
  float* out = (float*)d_out;                    // [1,4096,1024] fp32

  char* ws = (char*)d_ws;
  bf16* qkv   = (bf16*)ws;                    // 24 MiB (dead after qkv_post)
  bf16* xbf   = (bf16*)(ws + 25165824);       // 8 MiB  (dead after gemm1)
  bf16* wqkv  = (bf16*)(ws + 33554432);       // 6 MiB  (dead after gemm1)
  bf16* wproj = (bf16*)(ws + 39845888);       // 2 MiB
  bf16* qn    = (bf16*)(ws + 41943040);       // 8 MiB
  bf16* kn    = (bf16*)(ws + 50331648);       // 8 MiB
  bf16* vt    = (bf16*)(ws + 58720256);       // 8 MiB  [H][128][T]
  // flash partials ALIAS dead regions (stream-ordered: flash runs after
  // gemm1/qkv_post consumed them):
  float* Op  = (float*)ws;                    // 32 MiB  [512][128][128] f32
  float* lsw = (float*)(ws + 33554432);       // 256 KiB [512][128] f32

  cast3_f32_bf16<<<2048, 256, 0, stream>>>(x, xbf, 4194304 / 4, qkv_w, wqkv,
                                           3145728 / 4, c_proj, wproj,
                                           1048576 / 4);

  gemm_bt<1024, 3072, 128, 24, bf16><<<768, 256, 0, stream>>>(xbf, wqkv, qkv);

  qkv_post<<<dim3(8, 64), 256, 0, stream>>>(qkv, ve, lambdas, qn, kn, vt);

  flash_attn<<<512, 256, 0, stream>>>(qn, kn, vt, Op, lsw);

  gemm_proj<<<512, 256, 0, stream>>>(Op, lsw, wproj, out);
}

// Round 8
// 238.038 us; speedup vs baseline: 1.4901x; 1.0065x over previous
//
#include <hip/hip_runtime.h>

typedef __bf16 bf16;
typedef __bf16 bf16x8 __attribute__((ext_vector_type(8)));
typedef __bf16 bf16x4 __attribute__((ext_vector_type(4)));
typedef __bf16 bf16x2 __attribute__((ext_vector_type(2)));
typedef float f32x4 __attribute__((ext_vector_type(4)));
typedef float f32x16 __attribute__((ext_vector_type(16)));
typedef int i32x4 __attribute__((ext_vector_type(4)));
typedef int i32x2 __attribute__((ext_vector_type(2)));

#define GLL16(gp, lp)                                                          \
  __builtin_amdgcn_global_load_lds(                                            \
      (const __attribute__((address_space(1))) unsigned int*)(gp),             \
      (__attribute__((address_space(3))) unsigned int*)(lp), 16, 0, 0)

// ------------------------------------------------------- fused fp32->bf16 casts
__global__ __launch_bounds__(256) void cast3_f32_bf16(
    const float* __restrict__ a, bf16* __restrict__ oa, int na4,
    const float* __restrict__ b, bf16* __restrict__ ob, int nb4,
    const float* __restrict__ c, bf16* __restrict__ oc, int nc4) {
  int i = blockIdx.x * blockDim.x + threadIdx.x;
  int stride = gridDim.x * blockDim.x;
  int total = na4 + nb4 + nc4;
  for (; i < total; i += stride) {
    const float4* src;
    bf16x4* dst;
    int j = i;
    if (j < na4) {
      src = (const float4*)a + j; dst = (bf16x4*)oa + j;
    } else if ((j -= na4) < nb4) {
      src = (const float4*)b + j; dst = (bf16x4*)ob + j;
    } else {
      j -= nb4;
      src = (const float4*)c + j; dst = (bf16x4*)oc + j;
    }
    float4 v = *src;
    bf16x4 o;
    o[0] = (bf16)v.x; o[1] = (bf16)v.y; o[2] = (bf16)v.z; o[3] = (bf16)v.w;
    *dst = o;
  }
}

// ---------------------------------------------------------------- GEMM C = A * B^T
// Round-5 proven form: 2D dispatch, BM in {128, 64}.
template <int K, int LDC, int BM, typename CT>
__global__ __launch_bounds__(256) void gemm_bt(
    const bf16* __restrict__ A, const bf16* __restrict__ B,
    CT* __restrict__ C) {
  __shared__ __align__(16) bf16 As[BM * 64];
  __shared__ __align__(16) bf16 Bs[128 * 64];
  const int tid  = threadIdx.x;
  const int lane = tid & 63;
  const int wave = tid >> 6;
  const int ln15 = lane & 15, quad = lane >> 4;
  const int wm = wave >> 1, wn = wave & 1;
  const int m0 = blockIdx.y * BM, n0 = blockIdx.x * 128;
  constexpr int MI = BM / 32;  // 16-row m-frags per wave

  f32x4 acc[MI][4] = {};

  for (int k0 = 0; k0 < K; k0 += 64) {
    __syncthreads();
#pragma unroll
    for (int j = 0; j < BM / 32; ++j) {
      int gbase = j * 256 + wave * 64;
      int g = gbase + lane;
      int r = g >> 3, c = (g & 7) ^ (r & 7);
      GLL16(A + (size_t)(m0 + r) * K + k0 + c * 8, As + (size_t)gbase * 8);
    }
#pragma unroll
    for (int j = 0; j < 4; ++j) {
      int gbase = j * 256 + wave * 64;
      int g = gbase + lane;
      int r = g >> 3, c = (g & 7) ^ (r & 7);
      GLL16(B + (size_t)(n0 + r) * K + k0 + c * 8, Bs + (size_t)gbase * 8);
    }
    __syncthreads();
#pragma unroll
    for (int kk = 0; kk < 2; ++kk) {
      bf16x8 af[MI], bfr[4];
#pragma unroll
      for (int mi = 0; mi < MI; ++mi) {
        int m = wm * (BM / 2) + mi * 16 + ln15;
        int cg = kk * 4 + quad;
        af[mi] = *(const bf16x8*)(As + (m * 8 + (cg ^ (m & 7))) * 8);
      }
#pragma unroll
      for (int ni = 0; ni < 4; ++ni) {
        int n = wn * 64 + ni * 16 + ln15;
        int cg = kk * 4 + quad;
        bfr[ni] = *(const bf16x8*)(Bs + (n * 8 + (cg ^ (n & 7))) * 8);
      }
#pragma unroll
      for (int mi = 0; mi < MI; ++mi)
#pragma unroll
        for (int ni = 0; ni < 4; ++ni)
          acc[mi][ni] = __builtin_amdgcn_mfma_f32_16x16x32_bf16(
              af[mi], bfr[ni], acc[mi][ni], 0, 0, 0);
    }
  }
#pragma unroll
  for (int mi = 0; mi < MI; ++mi)
#pragma unroll
    for (int ni = 0; ni < 4; ++ni)
#pragma unroll
      for (int r = 0; r < 4; ++r) {
        int row = m0 + wm * (BM / 2) + mi * 16 + quad * 4 + r;
        int col = n0 + wn * 64 + ni * 16 + ln15;
        C[(size_t)row * LDC + col] = (CT)acc[mi][ni][r];
      }
}

// ---------------------------------------------------------------- qkv epilogue
__global__ __launch_bounds__(256) void qkv_post(
    const bf16* __restrict__ qkv, const float* __restrict__ ve,
    const float* __restrict__ lambdas, bf16* __restrict__ qn,
    bf16* __restrict__ kn, bf16* __restrict__ vt) {
  const int h  = blockIdx.x;
  const int t0 = blockIdx.y * 64;
  const int tid = threadIdx.x;
  const int wave = tid >> 6, lane = tid & 63;
  const int l31 = lane & 31, hl = lane >> 5;
  __shared__ __align__(16) float tile[64][129];

  // ---- q,k: rms + rotary (16 rows per wave, q and k per row)
  const int d0 = 2 * l31 + 64 * hl;
  const int trow0 = t0 + wave * 16;
  float ca0 = 1.f, sa0 = 0.f, ca1 = 1.f, sa1 = 0.f;  // per-row increment
  float c0 = 1.f, s0 = 0.f, c1 = 1.f, s1 = 0.f;      // current row angle
  if (l31 < 16) {
    float a0 = exp2f((float)(2 * l31) * (-10.0f / 31.0f));
    float a1 = exp2f((float)(2 * l31 + 1) * (-10.0f / 31.0f));
    __sincosf(a0, &sa0, &ca0);
    __sincosf(a1, &sa1, &ca1);
    __sincosf((float)trow0 * a0, &s0, &c0);
    __sincosf((float)trow0 * a1, &s1, &c1);
  }

  for (int i = 0; i < 16; ++i) {
    int t = trow0 + i;
    float s0m = hl ? -s0 : s0;
    float s1m = hl ? -s1 : s1;
#pragma unroll
    for (int qk = 0; qk < 2; ++qk) {
      const bf16* row = qkv + (size_t)t * 3072 + qk * 1024 + h * 128;
      bf16x2 xp = *(const bf16x2*)(row + d0);
      float xa = (float)xp[0], xb = (float)xp[1];
      float ss = xa * xa + xb * xb;
#pragma unroll
      for (int m = 1; m < 64; m <<= 1) ss += __shfl_xor(ss, m, 64);
      float rinv = rsqrtf(ss * (1.0f / 128.0f) + 1.1920929e-7f);
      if (qk == 0) rinv *= 0.12f;  // fold ATTN_SCALE into q
      float pa = __shfl_xor(xa, 32, 64);
      float pb = __shfl_xor(xb, 32, 64);
      float ya = (xa * c0 + pa * s0m) * rinv;
      float yb2 = (xb * c1 + pb * s1m) * rinv;
      bf16* orow = (qk == 0 ? qn : kn) + (size_t)t * 1024 + h * 128;
      bf16x2 o; o[0] = (bf16)ya; o[1] = (bf16)yb2;
      *(bf16x2*)(orow + d0) = o;
    }
    float nc0 = c0 * ca0 - s0 * sa0, ns0 = s0 * ca0 + c0 * sa0;
    float nc1 = c1 * ca1 - s1 * sa1, ns1 = s1 * ca1 + c1 * sa1;
    c0 = nc0; s0 = ns0; c1 = nc1; s1 = ns1;
  }

  // ---- v: lambda-mix + transpose to vt[d][T]
  float l0 = lambdas[0], l1 = lambdas[1];
  for (int c = 0; c < 16; ++c) {
    int idx = c * 512 + tid * 2;
    int d = idx & 127, tl = idx >> 7;
    int t = t0 + tl;
    bf16x2 vp = *(const bf16x2*)(qkv + (size_t)t * 3072 + 2048 + h * 128 + d);
    float2 vev = *(const float2*)(ve + (size_t)t * 1024 + h * 128 + d);
    tile[tl][d]     = l0 * (float)vp[0] + l1 * vev.x;
    tile[tl][d + 1] = l0 * (float)vp[1] + l1 * vev.y;
  }
  __syncthreads();
  for (int c = 0; c < 16; ++c) {
    int idx = c * 512 + tid * 2;
    int tl = idx & 63, d = idx >> 6;  // two consecutive t, same d
    bf16x2 o;
    o[0] = (bf16)tile[tl][d];
    o[1] = (bf16)tile[tl + 1][d];
    *(bf16x2*)(vt + ((size_t)(h * 128 + d)) * 4096 + t0 + tl) = o;
  }
}

// ---------------------------------------------------------------- flash attention
// Round 18: 8-wave blocks (512 thr), QBLK 256, kv-halves, grid 256 (1/CU,
// all-resident). Per-wave compute core identical to the proven r13 kernel;
// each staged 32KB K/V tile now serves 256 q rows instead of 128 -> staging
// bytes, GLL16 LDS writes, and barriers per unit work all halve. LDS-read
// floor unchanged (each wave still reads the full tile). No fences/atomics.
__global__ __launch_bounds__(512, 2) void flash_attn(
    const bf16* __restrict__ qn, const bf16* __restrict__ kn,
    const bf16* __restrict__ vt, float* __restrict__ Op,
    float* __restrict__ ls) {
  const int id = blockIdx.x;      // 0..255
  const int qt = 15 - (id >> 4);  // long blocks first
  const int sub = id & 15;
  const int h = sub >> 1;
  const int half = sub & 1;
  const int tid = threadIdx.x;    // 0..511
  const int wave = tid >> 6;      // 0..7
  const int lane = tid & 63;
  const int l31 = lane & 31, hl = lane >> 5;

  __shared__ __align__(16) bf16 smem[4 * 64 * 128];  // 64 KB: Ks(2x16K)+Vs(2x16K)
  bf16* Ks = smem;                  // [buf][kv][16 gran] ^(kv&15)
  bf16* Vs = smem + 2 * 64 * 128;   // [buf][d][8 gran]  ^(d&7)

  const int nkv = 4 * (qt + 1);
  const int half0 = 2 * (qt + 1);
  const int kt_begin = half ? half0 : 0;
  const int kt_end = half ? nkv : half0;
  const int niter = kt_end - kt_begin;  // = 2(qt+1) >= 2
  const int pidx = (h * 16 + qt) * 2 + half;

  const int qminw = qt * 256 + wave * 32;  // this wave's lowest q row
  const int qg = qminw + l31;              // this lane's q (B n-dim / C col)

  // Q B-frags (B[k=d][n=q], k=(lane>>5)*8+j): 8 frags cover d=0..127.
  bf16x8 qf[8];
  {
    const bf16* qb = qn + (size_t)qg * 1024 + h * 128 + hl * 8;
#pragma unroll
    for (int f = 0; f < 8; ++f) qf[f] = *(const bf16x8*)(qb + f * 16);
  }

  f32x16 acc_o[4] = {};  // O^T[d=dt*32+..][q 32] for this wave
  float rs = 0.0f;

  auto prefetch = [&](int kt, int buf) {
    const int kv0 = kt * 64;
    bf16* ks = Ks + buf * (64 * 128);
    bf16* vs = Vs + buf * (128 * 64);
#pragma unroll
    for (int jj = 0; jj < 2; ++jj) {  // K tile: 64 rows x 16 granules (1024)
      int gbase = jj * 512 + wave * 64;
      int g = gbase + lane;
      int r = g >> 4, c = (g & 15) ^ (r & 15);
      GLL16(kn + (size_t)(kv0 + r) * 1024 + h * 128 + c * 8,
            ks + (size_t)gbase * 8);
    }
#pragma unroll
    for (int jj = 0; jj < 2; ++jj) {  // V^T tile: 128 rows x 8 granules (1024)
      int gbase = jj * 512 + wave * 64;
      int g = gbase + lane;
      int d = g >> 3, c = (g & 7) ^ (d & 7);
      GLL16(vt + ((size_t)(h * 128 + d)) * 4096 + kv0 + c * 8,
            vs + (size_t)gbase * 8);
    }
  };

  prefetch(kt_begin, 0);

  for (int it = 0; it < niter; ++it) {
    const int kt = kt_begin + it;
    const int kv0 = kt * 64;
    __syncthreads();  // drains this wave's GLL16s; gates buffer reuse
    if (it + 1 < niter) prefetch(kt + 1, (it + 1) & 1);
    const bf16* ksb = Ks + (it & 1) * (64 * 128);
    const bf16* vsb = Vs + (it & 1) * (128 * 64);

    if (kv0 > qminw + 31) continue;  // wave-uniform: tile entirely above diag

    // ---- S^T = K-tile * Q^T: kv-half chains acc0 (rows 0..31), acc1 (32..63)
    f32x16 acc0 = {}, acc1 = {};
    const int l15 = l31 & 15;
    __builtin_amdgcn_s_setprio(1);
#pragma unroll
    for (int f = 0; f < 8; ++f) {
      bf16x8 a0 = *(const bf16x8*)(
          ksb + (l31 * 16 + ((2 * f + hl) ^ l15)) * 8);
      bf16x8 a1 = *(const bf16x8*)(
          ksb + ((32 + l31) * 16 + ((2 * f + hl) ^ l15)) * 8);
      acc0 = __builtin_amdgcn_mfma_f32_32x32x16_bf16(a0, qf[f], acc0, 0, 0, 0);
      acc1 = __builtin_amdgcn_mfma_f32_32x32x16_bf16(a1, qf[f], acc1, 0, 0, 0);
    }
    __builtin_amdgcn_s_setprio(0);

    // ---- exp + causal mask (C row = (r&3)+8*(r>>2)+4*hl); mask only near diag
    const bool needmask = (kv0 + 63 > qminw);
    float rsp[4] = {0.f, 0.f, 0.f, 0.f};
    if (needmask) {
#pragma unroll
      for (int rr = 0; rr < 16; ++rr) {
        int kvl = (rr & 3) + 8 * (rr >> 2) + 4 * hl;
        float v0 = __expf(acc0[rr]);
        float v1 = __expf(acc1[rr]);
        if (kv0 + kvl > qg) v0 = 0.0f;
        if (kv0 + 32 + kvl > qg) v1 = 0.0f;
        acc0[rr] = v0; acc1[rr] = v1;
        rsp[rr & 3] += v0 + v1;
      }
    } else {
#pragma unroll
      for (int rr = 0; rr < 16; ++rr) {
        float v0 = __expf(acc0[rr]);
        float v1 = __expf(acc1[rr]);
        acc0[rr] = v0; acc1[rr] = v1;
        rsp[rr & 3] += v0 + v1;
      }
    }
    rs += (rsp[0] + rsp[1]) + (rsp[2] + rsp[3]);

    // pack kv-pairs: pkX[g] = (kv base(g)+4hl, +1), base(g)=8*(g>>1)+2*(g&1)
    int pk0[8], pk1[8];
#pragma unroll
    for (int g = 0; g < 8; ++g) {
      bf16x2 t0, t1;
      t0[0] = (bf16)acc0[2 * g]; t0[1] = (bf16)acc0[2 * g + 1];
      t1[0] = (bf16)acc1[2 * g]; t1[1] = (bf16)acc1[2 * g + 1];
      pk0[g] = __builtin_bit_cast(int, t0);
      pk1[g] = __builtin_bit_cast(int, t1);
    }

    // ---- in-register transpose to PV B-frags; chunk cc covers kv [cc*16,+16)
    bf16x8 pf[4];
#if __has_builtin(__builtin_amdgcn_permlane32_swap)
#pragma unroll
    for (int cc = 0; cc < 4; ++cc) {
      int s0 = (cc < 2) ? pk0[(cc & 1) * 4 + 0] : pk1[(cc & 1) * 4 + 0];
      int s1 = (cc < 2) ? pk0[(cc & 1) * 4 + 1] : pk1[(cc & 1) * 4 + 1];
      int s2 = (cc < 2) ? pk0[(cc & 1) * 4 + 2] : pk1[(cc & 1) * 4 + 2];
      int s3 = (cc < 2) ? pk0[(cc & 1) * 4 + 3] : pk1[(cc & 1) * 4 + 3];
      i32x2 r02 = __builtin_amdgcn_permlane32_swap(s0, s2, false, false);
      i32x2 r13 = __builtin_amdgcn_permlane32_swap(s1, s3, false, false);
      i32x4 dv;
      dv[0] = r02[0];  // t=0: src half 0
      dv[1] = r13[0];  // t=1: src half 0
      dv[2] = r02[1];  // t=2: src half 1
      dv[3] = r13[1];  // t=3: src half 1
      pf[cc] = __builtin_bit_cast(bf16x8, dv);
    }
#else
#pragma unroll
    for (int cc = 0; cc < 4; ++cc) {
      int s0 = (cc < 2) ? pk0[(cc & 1) * 4 + 0] : pk1[(cc & 1) * 4 + 0];
      int s1 = (cc < 2) ? pk0[(cc & 1) * 4 + 1] : pk1[(cc & 1) * 4 + 1];
      int s2 = (cc < 2) ? pk0[(cc & 1) * 4 + 2] : pk1[(cc & 1) * 4 + 2];
      int s3 = (cc < 2) ? pk0[(cc & 1) * 4 + 3] : pk1[(cc & 1) * 4 + 3];
      int sh0 = __shfl_xor(s0, 32, 64);
      int sh1 = __shfl_xor(s1, 32, 64);
      int sh2 = __shfl_xor(s2, 32, 64);
      int sh3 = __shfl_xor(s3, 32, 64);
      int own0 = hl ? s2 : s0;
      int own1 = hl ? s3 : s1;
      int par0 = hl ? sh2 : sh0;
      int par1 = hl ? sh3 : sh1;
      i32x4 dv;
      dv[0] = hl ? par0 : own0;
      dv[1] = hl ? par1 : own1;
      dv[2] = hl ? own0 : par0;
      dv[3] = hl ? own1 : par1;
      pf[cc] = __builtin_bit_cast(bf16x8, dv);
    }
#endif

    // ---- O^T[d][q] += V^T-tile * P^T; V kv-granule = 2*cc + hl
    __builtin_amdgcn_s_setprio(1);
#pragma unroll
    for (int dt = 0; dt < 4; ++dt) {
      int vrow = dt * 32 + l31;
#pragma unroll
      for (int cc = 0; cc < 4; ++cc) {
        bf16x8 a = *(const bf16x8*)(
            vsb + (vrow * 8 + ((2 * cc + hl) ^ (vrow & 7))) * 8);
        acc_o[dt] =
            __builtin_amdgcn_mfma_f32_32x32x16_bf16(a, pf[cc], acc_o[dt], 0, 0, 0);
      }
    }
    __builtin_amdgcn_s_setprio(0);
  }

  // ---- epilogue: each wave owns q rows [wave*32, +32) — direct float4 stores
  rs += __shfl_xor(rs, 32, 64);
  if (hl == 0) ls[pidx * 256 + wave * 32 + l31] = rs;
  float* opb = Op + (size_t)pidx * 32768 + (size_t)(wave * 32 + l31) * 128;
#pragma unroll
  for (int dt = 0; dt < 4; ++dt)
#pragma unroll
    for (int rg = 0; rg < 4; ++rg) {
      float4 o;
      o.x = acc_o[dt][rg * 4 + 0];
      o.y = acc_o[dt][rg * 4 + 1];
      o.z = acc_o[dt][rg * 4 + 2];
      o.w = acc_o[dt][rg * 4 + 3];
      int d0 = dt * 32 + 4 * hl + 8 * rg;
      *(float4*)(opb + d0) = o;
    }
}

// ---------------------------------------------------------------- combine halves
// y[t][h*128+d] = (Op[h,qt,0] + Op[h,qt,1]) / (l0 + l1), bf16. qt tiles of 256.
__global__ __launch_bounds__(256) void attn_combine(
    const float* __restrict__ Op, const float* __restrict__ ls,
    bf16* __restrict__ y) {
  int gid = blockIdx.x * 256 + threadIdx.x;  // one float4 of output each
  int t = gid >> 8;
  int c4 = gid & 255;
  int qt = t >> 8, ql = t & 255;
  int h = c4 >> 5;
  int d = (c4 & 31) * 4;
  int pb = (h * 16 + qt) * 2;
  const float4 o0 = *(const float4*)(Op + (size_t)pb * 32768 + ql * 128 + d);
  const float4 o1 =
      *(const float4*)(Op + (size_t)(pb + 1) * 32768 + ql * 128 + d);
  float inv = 1.0f / (ls[pb * 256 + ql] + ls[(pb + 1) * 256 + ql]);
  bf16x4 o;
  o[0] = (bf16)((o0.x + o1.x) * inv);
  o[1] = (bf16)((o0.y + o1.y) * inv);
  o[2] = (bf16)((o0.z + o1.z) * inv);
  o[3] = (bf16)((o0.w + o1.w) * inv);
  *(bf16x4*)(y + (size_t)t * 1024 + h * 128 + d) = o;
}

// ---------------------------------------------------------------- launch
extern "C" void kernel_launch(void* const* d_in, const int* in_sizes, int n_in,
                              void* d_out, int out_size, void* d_ws,
                              size_t ws_size, hipStream_t stream) {
  const float* x       = (const float*)d_in[0];  // [1,4096,1024]
  const float* ve      = (const float*)d_in[1];  // [1,4096,1024]
  const float* qkv_w   = (const float*)d_in[2];  // [3,1024,1024]
  const float* lambdas = (const float*)d_in[3];  // [2]
  const float* c_proj  = (const float*)d_in[4];  // [1024,1024]
  float* out = (float*)d_out;                    // [1,4096,1024] fp32

  char* ws = (char*)d_ws;
  bf16* qkv   = (bf16*)ws;                    // 24 MiB (dead after qkv_post)
  bf16* xbf   = (bf16*)(ws + 25165824);       // 8 MiB  (dead after gemm1)
  bf16* wqkv  = (bf16*)(ws + 33554432);       // 6 MiB  (dead after gemm1)
  bf16* wproj = (bf16*)(ws + 39845888);       // 2 MiB
  bf16* qn    = (bf16*)(ws + 41943040);       // 8 MiB
  bf16* kn    = (bf16*)(ws + 50331648);       // 8 MiB
  bf16* vt    = (bf16*)(ws + 58720256);       // 8 MiB  [H][128][T]
  bf16* yb    = (bf16*)(ws + 67108864);       // 8 MiB
  // flash partials ALIAS dead regions (stream-ordered: flash runs after
  // gemm1/qkv_post consumed them):
  float* Op  = (float*)ws;                    // 32 MiB  [256][256][128] f32
  float* lsw = (float*)(ws + 33554432);       // 256 KiB [256][256] f32

  cast3_f32_bf16<<<2048, 256, 0, stream>>>(x, xbf, 4194304 / 4, qkv_w, wqkv,
                                           3145728 / 4, c_proj, wproj,
                                           1048576 / 4);

  gemm_bt<1024, 3072, 128, bf16><<<dim3(24, 32), 256, 0, stream>>>(xbf, wqkv,
                                                                   qkv);

  qkv_post<<<dim3(8, 64), 256, 0, stream>>>(qkv, ve, lambdas, qn, kn, vt);

  flash_attn<<<256, 512, 0, stream>>>(qn, kn, vt, Op, lsw);
  attn_combine<<<4096, 256, 0, stream>>>(Op, lsw, yb);

  gemm_bt<1024, 1024, 64, float><<<dim3(8, 64), 256, 0, stream>>>(yb, wproj,
                                                                  out);
}

// Round 9
// 218.171 us; speedup vs baseline: 1.6258x; 1.0911x over previous
//
#include <hip/hip_runtime.h>

typedef __bf16 bf16;
typedef __bf16 bf16x8 __attribute__((ext_vector_type(8)));
typedef __bf16 bf16x4 __attribute__((ext_vector_type(4)));
typedef __bf16 bf16x2 __attribute__((ext_vector_type(2)));
typedef float f32x4 __attribute__((ext_vector_type(4)));
typedef float f32x16 __attribute__((ext_vector_type(16)));
typedef int i32x4 __attribute__((ext_vector_type(4)));
typedef int i32x2 __attribute__((ext_vector_type(2)));

#define GLL16(gp, lp)                                                          \
  __builtin_amdgcn_global_load_lds(                                            \
      (const __attribute__((address_space(1))) unsigned int*)(gp),             \
      (__attribute__((address_space(3))) unsigned int*)(lp), 16, 0, 0)

// ------------------------------------------------------- fused fp32->bf16 casts
__global__ __launch_bounds__(256) void cast3_f32_bf16(
    const float* __restrict__ a, bf16* __restrict__ oa, int na4,
    const float* __restrict__ b, bf16* __restrict__ ob, int nb4,
    const float* __restrict__ c, bf16* __restrict__ oc, int nc4) {
  int i = blockIdx.x * blockDim.x + threadIdx.x;
  int stride = gridDim.x * blockDim.x;
  int total = na4 + nb4 + nc4;
  for (; i < total; i += stride) {
    const float4* src;
    bf16x4* dst;
    int j = i;
    if (j < na4) {
      src = (const float4*)a + j; dst = (bf16x4*)oa + j;
    } else if ((j -= na4) < nb4) {
      src = (const float4*)b + j; dst = (bf16x4*)ob + j;
    } else {
      j -= nb4;
      src = (const float4*)c + j; dst = (bf16x4*)oc + j;
    }
    float4 v = *src;
    bf16x4 o;
    o[0] = (bf16)v.x; o[1] = (bf16)v.y; o[2] = (bf16)v.z; o[3] = (bf16)v.w;
    *dst = o;
  }
}

// ---------------------------------------------------------------- GEMM C = A * B^T
// Round-5 proven form (2D dispatch). Used for the proj GEMM only.
template <int K, int LDC, int BM, typename CT>
__global__ __launch_bounds__(256) void gemm_bt(
    const bf16* __restrict__ A, const bf16* __restrict__ B,
    CT* __restrict__ C) {
  __shared__ __align__(16) bf16 As[BM * 64];
  __shared__ __align__(16) bf16 Bs[128 * 64];
  const int tid  = threadIdx.x;
  const int lane = tid & 63;
  const int wave = tid >> 6;
  const int ln15 = lane & 15, quad = lane >> 4;
  const int wm = wave >> 1, wn = wave & 1;
  const int m0 = blockIdx.y * BM, n0 = blockIdx.x * 128;
  constexpr int MI = BM / 32;

  f32x4 acc[MI][4] = {};

  for (int k0 = 0; k0 < K; k0 += 64) {
    __syncthreads();
#pragma unroll
    for (int j = 0; j < BM / 32; ++j) {
      int gbase = j * 256 + wave * 64;
      int g = gbase + lane;
      int r = g >> 3, c = (g & 7) ^ (r & 7);
      GLL16(A + (size_t)(m0 + r) * K + k0 + c * 8, As + (size_t)gbase * 8);
    }
#pragma unroll
    for (int j = 0; j < 4; ++j) {
      int gbase = j * 256 + wave * 64;
      int g = gbase + lane;
      int r = g >> 3, c = (g & 7) ^ (r & 7);
      GLL16(B + (size_t)(n0 + r) * K + k0 + c * 8, Bs + (size_t)gbase * 8);
    }
    __syncthreads();
#pragma unroll
    for (int kk = 0; kk < 2; ++kk) {
      bf16x8 af[MI], bfr[4];
#pragma unroll
      for (int mi = 0; mi < MI; ++mi) {
        int m = wm * (BM / 2) + mi * 16 + ln15;
        int cg = kk * 4 + quad;
        af[mi] = *(const bf16x8*)(As + (m * 8 + (cg ^ (m & 7))) * 8);
      }
#pragma unroll
      for (int ni = 0; ni < 4; ++ni) {
        int n = wn * 64 + ni * 16 + ln15;
        int cg = kk * 4 + quad;
        bfr[ni] = *(const bf16x8*)(Bs + (n * 8 + (cg ^ (n & 7))) * 8);
      }
#pragma unroll
      for (int mi = 0; mi < MI; ++mi)
#pragma unroll
        for (int ni = 0; ni < 4; ++ni)
          acc[mi][ni] = __builtin_amdgcn_mfma_f32_16x16x32_bf16(
              af[mi], bfr[ni], acc[mi][ni], 0, 0, 0);
    }
  }
#pragma unroll
  for (int mi = 0; mi < MI; ++mi)
#pragma unroll
    for (int ni = 0; ni < 4; ++ni)
#pragma unroll
      for (int r = 0; r < 4; ++r) {
        int row = m0 + wm * (BM / 2) + mi * 16 + quad * 4 + r;
        int col = n0 + wn * 64 + ni * 16 + ln15;
        C[(size_t)row * LDC + col] = (CT)acc[mi][ni][r];
      }
}

// ----------------------------------------- qkv GEMM with FUSED qkv epilogue
// C-tile [m0..m0+128) x [n0..n0+128) is exactly one (ck,h) slice with the
// full d-range (3072 = 3 ck x 8 h x 128 d), so rms/rotary/v-mix are block-
// local: spill acc -> LDS bf16 tile [128][130] (reuses staging LDS), then
// ck<2: per-row shfl sumsq + rotary + scaled write to qn/kn (round-0 math);
// ck==2: coalesced ve mix (t-major) then transposed bf16x2 write to vt.
// Deletes the qkv_post kernel + 24 MB qkv write + 24 MB re-read.
__global__ __launch_bounds__(256) void gemm_qkv(
    const bf16* __restrict__ A, const bf16* __restrict__ B,
    const float* __restrict__ ve, const float* __restrict__ lmb,
    bf16* __restrict__ qn, bf16* __restrict__ kn, bf16* __restrict__ vt) {
  __shared__ __align__(16) bf16 smem[128 * 131];  // 33.5 KB: staging + epi tile
  bf16* As = smem;             // [128][64] swizzled (16 KB)
  bf16* Bs = smem + 8192;      // [128][64] swizzled (16 KB)
  const int tid  = threadIdx.x;
  const int lane = tid & 63;
  const int wave = tid >> 6;
  const int ln15 = lane & 15, quad = lane >> 4;
  const int wm = wave >> 1, wn = wave & 1;
  const int m0 = blockIdx.y * 128, n0 = blockIdx.x * 128;

  f32x4 acc[4][4] = {};

  for (int k0 = 0; k0 < 1024; k0 += 64) {
    __syncthreads();
#pragma unroll
    for (int j = 0; j < 4; ++j) {
      int gbase = j * 256 + wave * 64;
      int g = gbase + lane;
      int r = g >> 3, c = (g & 7) ^ (r & 7);
      GLL16(A + (size_t)(m0 + r) * 1024 + k0 + c * 8, As + (size_t)gbase * 8);
    }
#pragma unroll
    for (int j = 0; j < 4; ++j) {
      int gbase = j * 256 + wave * 64;
      int g = gbase + lane;
      int r = g >> 3, c = (g & 7) ^ (r & 7);
      GLL16(B + (size_t)(n0 + r) * 1024 + k0 + c * 8, Bs + (size_t)gbase * 8);
    }
    __syncthreads();
#pragma unroll
    for (int kk = 0; kk < 2; ++kk) {
      bf16x8 af[4], bfr[4];
#pragma unroll
      for (int mi = 0; mi < 4; ++mi) {
        int m = wm * 64 + mi * 16 + ln15;
        int cg = kk * 4 + quad;
        af[mi] = *(const bf16x8*)(As + (m * 8 + (cg ^ (m & 7))) * 8);
      }
#pragma unroll
      for (int ni = 0; ni < 4; ++ni) {
        int n = wn * 64 + ni * 16 + ln15;
        int cg = kk * 4 + quad;
        bfr[ni] = *(const bf16x8*)(Bs + (n * 8 + (cg ^ (n & 7))) * 8);
      }
#pragma unroll
      for (int mi = 0; mi < 4; ++mi)
#pragma unroll
        for (int ni = 0; ni < 4; ++ni)
          acc[mi][ni] = __builtin_amdgcn_mfma_f32_16x16x32_bf16(
              af[mi], bfr[ni], acc[mi][ni], 0, 0, 0);
    }
  }

  // ---- fused epilogue: spill C-tile to LDS (staging buffers are dead)
  __syncthreads();
  bf16* tile = smem;  // [128][130]
#pragma unroll
  for (int mi = 0; mi < 4; ++mi)
#pragma unroll
    for (int ni = 0; ni < 4; ++ni)
#pragma unroll
      for (int r = 0; r < 4; ++r) {
        int row = wm * 64 + mi * 16 + quad * 4 + r;
        int col = wn * 64 + ni * 16 + ln15;
        tile[row * 130 + col] = (bf16)acc[mi][ni][r];
      }
  __syncthreads();

  const int ck = n0 >> 10;        // 0=q, 1=k, 2=v
  const int h  = (n0 >> 7) & 7;

  if (ck < 2) {
    // rms + rotary; each wave owns 32 rows, all 64 lanes per row.
    const int j = lane;
    bf16* outb = (ck == 0 ? qn : kn);
    float ang = 0.f;
    if (j < 32) ang = exp2f((float)j * (-10.0f / 31.0f));
    for (int i = 0; i < 32; ++i) {
      int row = wave * 32 + i;
      int t = m0 + row;
      float x1 = (float)tile[row * 130 + j];
      float x2 = (float)tile[row * 130 + j + 64];
      float ss = x1 * x1 + x2 * x2;
#pragma unroll
      for (int m = 1; m < 64; m <<= 1) ss += __shfl_xor(ss, m, 64);
      float rinv = rsqrtf(ss * (1.0f / 128.0f) + 1.1920929e-7f);
      if (ck == 0) rinv *= 0.12f;  // fold ATTN_SCALE into q
      float c = 1.0f, s = 0.0f;
      if (j < 32) __sincosf((float)t * ang, &s, &c);
      float y1 = (x1 * c + x2 * s) * rinv;
      float y2 = (x2 * c - x1 * s) * rinv;
      bf16* orow = outb + (size_t)t * 1024 + h * 128;
      orow[j] = (bf16)y1;
      orow[j + 64] = (bf16)y2;
    }
  } else {
    // v: lambda-mix with ve (t-major, coalesced), then transposed write to vt
    float l0 = lmb[0], l1 = lmb[1];
    for (int c = 0; c < 32; ++c) {
      int idx = c * 512 + tid * 2;
      int d = idx & 127, tl = idx >> 7;
      int t = m0 + tl;
      bf16x2 vp = *(bf16x2*)(tile + tl * 130 + d);
      float2 vev = *(const float2*)(ve + (size_t)t * 1024 + h * 128 + d);
      bf16x2 o;
      o[0] = (bf16)(l0 * (float)vp[0] + l1 * vev.x);
      o[1] = (bf16)(l0 * (float)vp[1] + l1 * vev.y);
      *(bf16x2*)(tile + tl * 130 + d) = o;
    }
    __syncthreads();
    for (int c = 0; c < 32; ++c) {
      int idx = c * 512 + tid * 2;
      int tl = idx & 127, d = idx >> 7;  // two consecutive t, same d
      bf16x2 o;
      o[0] = tile[tl * 130 + d];
      o[1] = tile[(tl + 1) * 130 + d];
      *(bf16x2*)(vt + ((size_t)(h * 128 + d)) * 4096 + m0 + tl) = o;
    }
  }
}

// ---------------------------------------------------------------- flash attention
// Round 13 core (proven 57.5 us over 3 reruns): QBLK 128, 4 waves x 32 q-rows,
// full 64-kv tile per iter, single-barrier GLL16-dbuf pipeline, grid 512
// (2 blocks/CU; cross-block overlap hides barrier drains). DO NOT MODIFY:
// chunked-LPT (r14), fused-combine+fence (r16), 8-wave/1-per-CU (r18) all lost.
__global__ __launch_bounds__(256, 2) void flash_attn(
    const bf16* __restrict__ qn, const bf16* __restrict__ kn,
    const bf16* __restrict__ vt, float* __restrict__ Op,
    float* __restrict__ ls) {
  const int id = blockIdx.x;  // 0..511
  const int qt = (id < 256) ? (31 - (id >> 4)) : ((id - 256) >> 4);
  const int sub = id & 15;
  const int h = sub >> 1;
  const int half = sub & 1;
  const int tid = threadIdx.x;
  const int wave = tid >> 6, lane = tid & 63;
  const int l31 = lane & 31, hl = lane >> 5;

  __shared__ __align__(16) bf16 smem[4 * 64 * 128];  // 64 KB: Ks(2x16K)+Vs(2x16K)
  bf16* Ks = smem;                  // [buf][kv][16 gran] ^(kv&15)
  bf16* Vs = smem + 2 * 64 * 128;   // [buf][d][8 gran]  ^(d&7)

  const int nkv = 2 * (qt + 1);
  const int half0 = qt + 1;
  const int kt_begin = half ? half0 : 0;
  const int kt_end = half ? nkv : half0;
  const int niter = kt_end - kt_begin;  // = qt+1 >= 1
  const int pidx = (h * 32 + qt) * 2 + half;

  const int qminw = qt * 128 + wave * 32;  // this wave's lowest q row
  const int qg = qminw + l31;              // this lane's q (B n-dim / C col)

  // Q B-frags (B[k=d][n=q], k=(lane>>5)*8+j): 8 frags cover d=0..127.
  bf16x8 qf[8];
  {
    const bf16* qb = qn + (size_t)qg * 1024 + h * 128 + hl * 8;
#pragma unroll
    for (int f = 0; f < 8; ++f) qf[f] = *(const bf16x8*)(qb + f * 16);
  }

  f32x16 acc_o[4] = {};  // O^T[d=dt*32+..][q 32] for this wave
  float rs = 0.0f;

  auto prefetch = [&](int kt, int buf) {
    const int kv0 = kt * 64;
    bf16* ks = Ks + buf * (64 * 128);
    bf16* vs = Vs + buf * (128 * 64);
#pragma unroll
    for (int jj = 0; jj < 4; ++jj) {  // K tile: 64 rows x 16 granules
      int gbase = jj * 256 + wave * 64;
      int g = gbase + lane;
      int r = g >> 4, c = (g & 15) ^ (r & 15);
      GLL16(kn + (size_t)(kv0 + r) * 1024 + h * 128 + c * 8,
            ks + (size_t)gbase * 8);
    }
#pragma unroll
    for (int jj = 0; jj < 4; ++jj) {  // V^T tile: 128 rows x 8 granules
      int gbase = jj * 256 + wave * 64;
      int g = gbase + lane;
      int d = g >> 3, c = (g & 7) ^ (d & 7);
      GLL16(vt + ((size_t)(h * 128 + d)) * 4096 + kv0 + c * 8,
            vs + (size_t)gbase * 8);
    }
  };

  prefetch(kt_begin, 0);

  for (int it = 0; it < niter; ++it) {
    const int kt = kt_begin + it;
    const int kv0 = kt * 64;
    __syncthreads();  // drains this wave's GLL16s; gates buffer reuse
    if (it + 1 < niter) prefetch(kt + 1, (it + 1) & 1);
    const bf16* ksb = Ks + (it & 1) * (64 * 128);
    const bf16* vsb = Vs + (it & 1) * (128 * 64);

    if (kv0 > qminw + 31) continue;  // wave-uniform: tile entirely above diag

    // ---- S^T = K-tile * Q^T: kv-half chains acc0 (rows 0..31), acc1 (32..63)
    f32x16 acc0 = {}, acc1 = {};
    const int l15 = l31 & 15;
    __builtin_amdgcn_s_setprio(1);
#pragma unroll
    for (int f = 0; f < 8; ++f) {
      bf16x8 a0 = *(const bf16x8*)(
          ksb + (l31 * 16 + ((2 * f + hl) ^ l15)) * 8);
      bf16x8 a1 = *(const bf16x8*)(
          ksb + ((32 + l31) * 16 + ((2 * f + hl) ^ l15)) * 8);
      acc0 = __builtin_amdgcn_mfma_f32_32x32x16_bf16(a0, qf[f], acc0, 0, 0, 0);
      acc1 = __builtin_amdgcn_mfma_f32_32x32x16_bf16(a1, qf[f], acc1, 0, 0, 0);
    }
    __builtin_amdgcn_s_setprio(0);

    // ---- exp + causal mask (C row = (r&3)+8*(r>>2)+4*hl); mask only near diag
    const bool needmask = (kv0 + 63 > qminw);
    float rsp[4] = {0.f, 0.f, 0.f, 0.f};
    if (needmask) {
#pragma unroll
      for (int rr = 0; rr < 16; ++rr) {
        int kvl = (rr & 3) + 8 * (rr >> 2) + 4 * hl;
        float v0 = __expf(acc0[rr]);
        float v1 = __expf(acc1[rr]);
        if (kv0 + kvl > qg) v0 = 0.0f;
        if (kv0 + 32 + kvl > qg) v1 = 0.0f;
        acc0[rr] = v0; acc1[rr] = v1;
        rsp[rr & 3] += v0 + v1;
      }
    } else {
#pragma unroll
      for (int rr = 0; rr < 16; ++rr) {
        float v0 = __expf(acc0[rr]);
        float v1 = __expf(acc1[rr]);
        acc0[rr] = v0; acc1[rr] = v1;
        rsp[rr & 3] += v0 + v1;
      }
    }
    rs += (rsp[0] + rsp[1]) + (rsp[2] + rsp[3]);

    // pack kv-pairs: pkX[g] = (kv base(g)+4hl, +1), base(g)=8*(g>>1)+2*(g&1)
    int pk0[8], pk1[8];
#pragma unroll
    for (int g = 0; g < 8; ++g) {
      bf16x2 t0, t1;
      t0[0] = (bf16)acc0[2 * g]; t0[1] = (bf16)acc0[2 * g + 1];
      t1[0] = (bf16)acc1[2 * g]; t1[1] = (bf16)acc1[2 * g + 1];
      pk0[g] = __builtin_bit_cast(int, t0);
      pk1[g] = __builtin_bit_cast(int, t1);
    }

    // ---- in-register transpose to PV B-frags; chunk cc covers kv [cc*16,+16)
    bf16x8 pf[4];
#if __has_builtin(__builtin_amdgcn_permlane32_swap)
#pragma unroll
    for (int cc = 0; cc < 4; ++cc) {
      int s0 = (cc < 2) ? pk0[(cc & 1) * 4 + 0] : pk1[(cc & 1) * 4 + 0];
      int s1 = (cc < 2) ? pk0[(cc & 1) * 4 + 1] : pk1[(cc & 1) * 4 + 1];
      int s2 = (cc < 2) ? pk0[(cc & 1) * 4 + 2] : pk1[(cc & 1) * 4 + 2];
      int s3 = (cc < 2) ? pk0[(cc & 1) * 4 + 3] : pk1[(cc & 1) * 4 + 3];
      i32x2 r02 = __builtin_amdgcn_permlane32_swap(s0, s2, false, false);
      i32x2 r13 = __builtin_amdgcn_permlane32_swap(s1, s3, false, false);
      i32x4 dv;
      dv[0] = r02[0];  // t=0: src half 0
      dv[1] = r13[0];  // t=1: src half 0
      dv[2] = r02[1];  // t=2: src half 1
      dv[3] = r13[1];  // t=3: src half 1
      pf[cc] = __builtin_bit_cast(bf16x8, dv);
    }
#else
#pragma unroll
    for (int cc = 0; cc < 4; ++cc) {
      int s0 = (cc < 2) ? pk0[(cc & 1) * 4 + 0] : pk1[(cc & 1) * 4 + 0];
      int s1 = (cc < 2) ? pk0[(cc & 1) * 4 + 1] : pk1[(cc & 1) * 4 + 1];
      int s2 = (cc < 2) ? pk0[(cc & 1) * 4 + 2] : pk1[(cc & 1) * 4 + 2];
      int s3 = (cc < 2) ? pk0[(cc & 1) * 4 + 3] : pk1[(cc & 1) * 4 + 3];
      int sh0 = __shfl_xor(s0, 32, 64);
      int sh1 = __shfl_xor(s1, 32, 64);
      int sh2 = __shfl_xor(s2, 32, 64);
      int sh3 = __shfl_xor(s3, 32, 64);
      int own0 = hl ? s2 : s0;
      int own1 = hl ? s3 : s1;
      int par0 = hl ? sh2 : sh0;
      int par1 = hl ? sh3 : sh1;
      i32x4 dv;
      dv[0] = hl ? par0 : own0;
      dv[1] = hl ? par1 : own1;
      dv[2] = hl ? own0 : par0;
      dv[3] = hl ? own1 : par1;
      pf[cc] = __builtin_bit_cast(bf16x8, dv);
    }
#endif

    // ---- O^T[d][q] += V^T-tile * P^T; V kv-granule = 2*cc + hl
    __builtin_amdgcn_s_setprio(1);
#pragma unroll
    for (int dt = 0; dt < 4; ++dt) {
      int vrow = dt * 32 + l31;
#pragma unroll
      for (int cc = 0; cc < 4; ++cc) {
        bf16x8 a = *(const bf16x8*)(
            vsb + (vrow * 8 + ((2 * cc + hl) ^ (vrow & 7))) * 8);
        acc_o[dt] =
            __builtin_amdgcn_mfma_f32_32x32x16_bf16(a, pf[cc], acc_o[dt], 0, 0, 0);
      }
    }
    __builtin_amdgcn_s_setprio(0);
  }

  // ---- epilogue: each wave owns q rows [wave*32, +32) — direct float4 stores
  rs += __shfl_xor(rs, 32, 64);
  if (hl == 0) ls[pidx * 128 + wave * 32 + l31] = rs;
  float* opb = Op + (size_t)pidx * 16384 + (size_t)(wave * 32 + l31) * 128;
#pragma unroll
  for (int dt = 0; dt < 4; ++dt)
#pragma unroll
    for (int rg = 0; rg < 4; ++rg) {
      float4 o;
      o.x = acc_o[dt][rg * 4 + 0];
      o.y = acc_o[dt][rg * 4 + 1];
      o.z = acc_o[dt][rg * 4 + 2];
      o.w = acc_o[dt][rg * 4 + 3];
      int d0 = dt * 32 + 4 * hl + 8 * rg;
      *(float4*)(opb + d0) = o;
    }
}

// ---------------------------------------------------------------- combine halves
// y[t][h*128+d] = (Op[h,qt,0] + Op[h,qt,1]) / (l0 + l1), bf16. qt tiles of 128.
__global__ __launch_bounds__(256) void attn_combine(
    const float* __restrict__ Op, const float* __restrict__ ls,
    bf16* __restrict__ y) {
  int gid = blockIdx.x * 256 + threadIdx.x;  // one float4 of output each
  int t = gid >> 8;
  int c4 = gid & 255;
  int qt = t >> 7, ql = t & 127;
  int h = c4 >> 5;
  int d = (c4 & 31) * 4;
  int pb = (h * 32 + qt) * 2;
  const float4 o0 = *(const float4*)(Op + (size_t)pb * 16384 + ql * 128 + d);
  const float4 o1 =
      *(const float4*)(Op + (size_t)(pb + 1) * 16384 + ql * 128 + d);
  float inv = 1.0f / (ls[pb * 128 + ql] + ls[(pb + 1) * 128 + ql]);
  bf16x4 o;
  o[0] = (bf16)((o0.x + o1.x) * inv);
  o[1] = (bf16)((o0.y + o1.y) * inv);
  o[2] = (bf16)((o0.z + o1.z) * inv);
  o[3] = (bf16)((o0.w + o1.w) * inv);
  *(bf16x4*)(y + (size_t)t * 1024 + h * 128 + d) = o;
}

// ---------------------------------------------------------------- launch
extern "C" void kernel_launch(void* const* d_in, const int* in_sizes, int n_in,
                              void* d_out, int out_size, void* d_ws,
                              size_t ws_size, hipStream_t stream) {
  const float* x       = (const float*)d_in[0];  // [1,4096,1024]
  const float* ve      = (const float*)d_in[1];  // [1,4096,1024]
  const float* qkv_w   = (const float*)d_in[2];  // [3,1024,1024]
  const float* lambdas = (const float*)d_in[3];  // [2]
  const float* c_proj  = (const float*)d_in[4];  // [1024,1024]
  float* out = (float*)d_out;                    // [1,4096,1024] fp32

  char* ws = (char*)d_ws;
  bf16* xbf   = (bf16*)ws;                    // 8 MiB  (dead after gemm_qkv)
  bf16* wqkv  = (bf16*)(ws + 8388608);        // 6 MiB  (dead after gemm_qkv)
  // flash partials ALIAS the dead prefix (stream-ordered):
  float* Op  = (float*)ws;                    // 32 MiB  [512][128][128] f32
  float* lsw = (float*)(ws + 33554432);       // 256 KiB [512][128] f32
  bf16* wproj = (bf16*)(ws + 33816576);       // 2 MiB
  bf16* qn    = (bf16*)(ws + 35913728);       // 8 MiB
  bf16* kn    = (bf16*)(ws + 44302336);       // 8 MiB
  bf16* vt    = (bf16*)(ws + 52690944);       // 8 MiB  [H][128][T]
  bf16* yb    = (bf16*)(ws + 61079552);       // 8 MiB

  cast3_f32_bf16<<<2048, 256, 0, stream>>>(x, xbf, 4194304 / 4, qkv_w, wqkv,
                                           3145728 / 4, c_proj, wproj,
                                           1048576 / 4);

  gemm_qkv<<<dim3(24, 32), 256, 0, stream>>>(xbf, wqkv, ve, lambdas, qn, kn,
                                             vt);

  flash_attn<<<512, 256, 0, stream>>>(qn, kn, vt, Op, lsw);
  attn_combine<<<4096, 256, 0, stream>>>(Op, lsw, yb);

  gemm_bt<1024, 1024, 64, float><<<dim3(8, 64), 256, 0, stream>>>(yb, wproj,
                                                                  out);
}

// Round 11
// 215.561 us; speedup vs baseline: 1.6455x; 1.0121x over previous
//
#include <hip/hip_runtime.h>

typedef __bf16 bf16;
typedef __bf16 bf16x8 __attribute__((ext_vector_type(8)));
typedef __bf16 bf16x4 __attribute__((ext_vector_type(4)));
typedef __bf16 bf16x2 __attribute__((ext_vector_type(2)));
typedef float f32x4 __attribute__((ext_vector_type(4)));
typedef float f32x16 __attribute__((ext_vector_type(16)));
typedef int i32x4 __attribute__((ext_vector_type(4)));
typedef int i32x2 __attribute__((ext_vector_type(2)));

#define GLL16(gp, lp)                                                          \
  __builtin_amdgcn_global_load_lds(                                            \
      (const __attribute__((address_space(1))) unsigned int*)(gp),             \
      (__attribute__((address_space(3))) unsigned int*)(lp), 16, 0, 0)

// ------------------------------------------------------- fused fp32->bf16 casts
__global__ __launch_bounds__(256) void cast3_f32_bf16(
    const float* __restrict__ a, bf16* __restrict__ oa, int na4,
    const float* __restrict__ b, bf16* __restrict__ ob, int nb4,
    const float* __restrict__ c, bf16* __restrict__ oc, int nc4) {
  int i = blockIdx.x * blockDim.x + threadIdx.x;
  int stride = gridDim.x * blockDim.x;
  int total = na4 + nb4 + nc4;
  for (; i < total; i += stride) {
    const float4* src;
    bf16x4* dst;
    int j = i;
    if (j < na4) {
      src = (const float4*)a + j; dst = (bf16x4*)oa + j;
    } else if ((j -= na4) < nb4) {
      src = (const float4*)b + j; dst = (bf16x4*)ob + j;
    } else {
      j -= nb4;
      src = (const float4*)c + j; dst = (bf16x4*)oc + j;
    }
    float4 v = *src;
    bf16x4 o;
    o[0] = (bf16)v.x; o[1] = (bf16)v.y; o[2] = (bf16)v.z; o[3] = (bf16)v.w;
    *dst = o;
  }
}

// ---------------------------------------------------------------- GEMM C = A * B^T
// Round-9 proven form (2D dispatch, two-barrier single-buffer). Proj GEMM only.
template <int K, int LDC, int BM, typename CT>
__global__ __launch_bounds__(256) void gemm_bt(
    const bf16* __restrict__ A, const bf16* __restrict__ B,
    CT* __restrict__ C) {
  __shared__ __align__(16) bf16 As[BM * 64];
  __shared__ __align__(16) bf16 Bs[128 * 64];
  const int tid  = threadIdx.x;
  const int lane = tid & 63;
  const int wave = tid >> 6;
  const int ln15 = lane & 15, quad = lane >> 4;
  const int wm = wave >> 1, wn = wave & 1;
  const int m0 = blockIdx.y * BM, n0 = blockIdx.x * 128;
  constexpr int MI = BM / 32;

  f32x4 acc[MI][4] = {};

  for (int k0 = 0; k0 < K; k0 += 64) {
    __syncthreads();
#pragma unroll
    for (int j = 0; j < BM / 32; ++j) {
      int gbase = j * 256 + wave * 64;
      int g = gbase + lane;
      int r = g >> 3, c = (g & 7) ^ (r & 7);
      GLL16(A + (size_t)(m0 + r) * K + k0 + c * 8, As + (size_t)gbase * 8);
    }
#pragma unroll
    for (int j = 0; j < 4; ++j) {
      int gbase = j * 256 + wave * 64;
      int g = gbase + lane;
      int r = g >> 3, c = (g & 7) ^ (r & 7);
      GLL16(B + (size_t)(n0 + r) * K + k0 + c * 8, Bs + (size_t)gbase * 8);
    }
    __syncthreads();
#pragma unroll
    for (int kk = 0; kk < 2; ++kk) {
      bf16x8 af[MI], bfr[4];
#pragma unroll
      for (int mi = 0; mi < MI; ++mi) {
        int m = wm * (BM / 2) + mi * 16 + ln15;
        int cg = kk * 4 + quad;
        af[mi] = *(const bf16x8*)(As + (m * 8 + (cg ^ (m & 7))) * 8);
      }
#pragma unroll
      for (int ni = 0; ni < 4; ++ni) {
        int n = wn * 64 + ni * 16 + ln15;
        int cg = kk * 4 + quad;
        bfr[ni] = *(const bf16x8*)(Bs + (n * 8 + (cg ^ (n & 7))) * 8);
      }
#pragma unroll
      for (int mi = 0; mi < MI; ++mi)
#pragma unroll
        for (int ni = 0; ni < 4; ++ni)
          acc[mi][ni] = __builtin_amdgcn_mfma_f32_16x16x32_bf16(
              af[mi], bfr[ni], acc[mi][ni], 0, 0, 0);
    }
  }
#pragma unroll
  for (int mi = 0; mi < MI; ++mi)
#pragma unroll
    for (int ni = 0; ni < 4; ++ni)
#pragma unroll
      for (int r = 0; r < 4; ++r) {
        int row = m0 + wm * (BM / 2) + mi * 16 + quad * 4 + r;
        int col = n0 + wn * 64 + ni * 16 + ln15;
        C[(size_t)row * LDC + col] = (CT)acc[mi][ni][r];
      }
}

// ----------------------------------------- qkv GEMM with FUSED qkv epilogue
// A/B round 21: ONLY change vs round 9 = flash-style single-barrier GLL16
// double-buffer in the K-loop (LDS 33.8K -> 64K, 2 blocks/CU). Epilogue is
// round-9 VERBATIM (per-row sincos — the round-10 vectorized version is
// suspected in the correctness failure and is not reintroduced).
__global__ __launch_bounds__(256) void gemm_qkv(
    const bf16* __restrict__ A, const bf16* __restrict__ B,
    const float* __restrict__ ve, const float* __restrict__ lmb,
    bf16* __restrict__ qn, bf16* __restrict__ kn, bf16* __restrict__ vt) {
  __shared__ __align__(16) bf16 smem[2 * 16384];  // 64 KB: 2 x (As 16K + Bs 16K)
  const int tid  = threadIdx.x;
  const int lane = tid & 63;
  const int wave = tid >> 6;
  const int ln15 = lane & 15, quad = lane >> 4;
  const int wm = wave >> 1, wn = wave & 1;
  const int m0 = blockIdx.y * 128, n0 = blockIdx.x * 128;

  f32x4 acc[4][4] = {};

  auto prefetch = [&](int kt, int buf) {
    const int k0 = kt * 64;
    bf16* As = smem + buf * 16384;
    bf16* Bs = As + 8192;
#pragma unroll
    for (int j = 0; j < 4; ++j) {
      int gbase = j * 256 + wave * 64;
      int g = gbase + lane;
      int r = g >> 3, c = (g & 7) ^ (r & 7);
      GLL16(A + (size_t)(m0 + r) * 1024 + k0 + c * 8, As + (size_t)gbase * 8);
    }
#pragma unroll
    for (int j = 0; j < 4; ++j) {
      int gbase = j * 256 + wave * 64;
      int g = gbase + lane;
      int r = g >> 3, c = (g & 7) ^ (r & 7);
      GLL16(B + (size_t)(n0 + r) * 1024 + k0 + c * 8, Bs + (size_t)gbase * 8);
    }
  };

  prefetch(0, 0);

  for (int kt = 0; kt < 16; ++kt) {
    __syncthreads();  // drains tile-kt GLL16s; gates buffer reuse
    if (kt + 1 < 16) prefetch(kt + 1, (kt + 1) & 1);
    const bf16* As = smem + (kt & 1) * 16384;
    const bf16* Bs = As + 8192;
#pragma unroll
    for (int kk = 0; kk < 2; ++kk) {
      bf16x8 af[4], bfr[4];
#pragma unroll
      for (int mi = 0; mi < 4; ++mi) {
        int m = wm * 64 + mi * 16 + ln15;
        int cg = kk * 4 + quad;
        af[mi] = *(const bf16x8*)(As + (m * 8 + (cg ^ (m & 7))) * 8);
      }
#pragma unroll
      for (int ni = 0; ni < 4; ++ni) {
        int n = wn * 64 + ni * 16 + ln15;
        int cg = kk * 4 + quad;
        bfr[ni] = *(const bf16x8*)(Bs + (n * 8 + (cg ^ (n & 7))) * 8);
      }
#pragma unroll
      for (int mi = 0; mi < 4; ++mi)
#pragma unroll
        for (int ni = 0; ni < 4; ++ni)
          acc[mi][ni] = __builtin_amdgcn_mfma_f32_16x16x32_bf16(
              af[mi], bfr[ni], acc[mi][ni], 0, 0, 0);
    }
  }

  // ---- fused epilogue: spill C-tile to LDS (staging buffers are dead)
  __syncthreads();
  bf16* tile = smem;  // [128][130] bf16 = 33.3 KB
#pragma unroll
  for (int mi = 0; mi < 4; ++mi)
#pragma unroll
    for (int ni = 0; ni < 4; ++ni)
#pragma unroll
      for (int r = 0; r < 4; ++r) {
        int row = wm * 64 + mi * 16 + quad * 4 + r;
        int col = wn * 64 + ni * 16 + ln15;
        tile[row * 130 + col] = (bf16)acc[mi][ni][r];
      }
  __syncthreads();

  const int ck = n0 >> 10;        // 0=q, 1=k, 2=v
  const int h  = (n0 >> 7) & 7;

  if (ck < 2) {
    // rms + rotary; each wave owns 32 rows, all 64 lanes per row. (round-9)
    const int j = lane;
    bf16* outb = (ck == 0 ? qn : kn);
    float ang = 0.f;
    if (j < 32) ang = exp2f((float)j * (-10.0f / 31.0f));
    for (int i = 0; i < 32; ++i) {
      int row = wave * 32 + i;
      int t = m0 + row;
      float x1 = (float)tile[row * 130 + j];
      float x2 = (float)tile[row * 130 + j + 64];
      float ss = x1 * x1 + x2 * x2;
#pragma unroll
      for (int m = 1; m < 64; m <<= 1) ss += __shfl_xor(ss, m, 64);
      float rinv = rsqrtf(ss * (1.0f / 128.0f) + 1.1920929e-7f);
      if (ck == 0) rinv *= 0.12f;  // fold ATTN_SCALE into q
      float c = 1.0f, s = 0.0f;
      if (j < 32) __sincosf((float)t * ang, &s, &c);
      float y1 = (x1 * c + x2 * s) * rinv;
      float y2 = (x2 * c - x1 * s) * rinv;
      bf16* orow = outb + (size_t)t * 1024 + h * 128;
      orow[j] = (bf16)y1;
      orow[j + 64] = (bf16)y2;
    }
  } else {
    // v: lambda-mix with ve (t-major, coalesced), then transposed write to vt
    float l0 = lmb[0], l1 = lmb[1];
    for (int c = 0; c < 32; ++c) {
      int idx = c * 512 + tid * 2;
      int d = idx & 127, tl = idx >> 7;
      int t = m0 + tl;
      bf16x2 vp = *(bf16x2*)(tile + tl * 130 + d);
      float2 vev = *(const float2*)(ve + (size_t)t * 1024 + h * 128 + d);
      bf16x2 o;
      o[0] = (bf16)(l0 * (float)vp[0] + l1 * vev.x);
      o[1] = (bf16)(l0 * (float)vp[1] + l1 * vev.y);
      *(bf16x2*)(tile + tl * 130 + d) = o;
    }
    __syncthreads();
    for (int c = 0; c < 32; ++c) {
      int idx = c * 512 + tid * 2;
      int tl = idx & 127, d = idx >> 7;  // two consecutive t, same d
      bf16x2 o;
      o[0] = tile[tl * 130 + d];
      o[1] = tile[(tl + 1) * 130 + d];
      *(bf16x2*)(vt + ((size_t)(h * 128 + d)) * 4096 + m0 + tl) = o;
    }
  }
}

// ---------------------------------------------------------------- flash attention
// Round 13 core (proven 57.5 us over 3 reruns): QBLK 128, 4 waves x 32 q-rows,
// full 64-kv tile per iter, single-barrier GLL16-dbuf pipeline, grid 512
// (2 blocks/CU; cross-block overlap hides barrier drains). DO NOT MODIFY:
// chunked-LPT (r14), fused-combine+fence (r16), 8-wave/1-per-CU (r18) all lost.
__global__ __launch_bounds__(256, 2) void flash_attn(
    const bf16* __restrict__ qn, const bf16* __restrict__ kn,
    const bf16* __restrict__ vt, float* __restrict__ Op,
    float* __restrict__ ls) {
  const int id = blockIdx.x;  // 0..511
  const int qt = (id < 256) ? (31 - (id >> 4)) : ((id - 256) >> 4);
  const int sub = id & 15;
  const int h = sub >> 1;
  const int half = sub & 1;
  const int tid = threadIdx.x;
  const int wave = tid >> 6, lane = tid & 63;
  const int l31 = lane & 31, hl = lane >> 5;

  __shared__ __align__(16) bf16 smem[4 * 64 * 128];  // 64 KB: Ks(2x16K)+Vs(2x16K)
  bf16* Ks = smem;                  // [buf][kv][16 gran] ^(kv&15)
  bf16* Vs = smem + 2 * 64 * 128;   // [buf][d][8 gran]  ^(d&7)

  const int nkv = 2 * (qt + 1);
  const int half0 = qt + 1;
  const int kt_begin = half ? half0 : 0;
  const int kt_end = half ? nkv : half0;
  const int niter = kt_end - kt_begin;  // = qt+1 >= 1
  const int pidx = (h * 32 + qt) * 2 + half;

  const int qminw = qt * 128 + wave * 32;  // this wave's lowest q row
  const int qg = qminw + l31;              // this lane's q (B n-dim / C col)

  // Q B-frags (B[k=d][n=q], k=(lane>>5)*8+j): 8 frags cover d=0..127.
  bf16x8 qf[8];
  {
    const bf16* qb = qn + (size_t)qg * 1024 + h * 128 + hl * 8;
#pragma unroll
    for (int f = 0; f < 8; ++f) qf[f] = *(const bf16x8*)(qb + f * 16);
  }

  f32x16 acc_o[4] = {};  // O^T[d=dt*32+..][q 32] for this wave
  float rs = 0.0f;

  auto prefetch = [&](int kt, int buf) {
    const int kv0 = kt * 64;
    bf16* ks = Ks + buf * (64 * 128);
    bf16* vs = Vs + buf * (128 * 64);
#pragma unroll
    for (int jj = 0; jj < 4; ++jj) {  // K tile: 64 rows x 16 granules
      int gbase = jj * 256 + wave * 64;
      int g = gbase + lane;
      int r = g >> 4, c = (g & 15) ^ (r & 15);
      GLL16(kn + (size_t)(kv0 + r) * 1024 + h * 128 + c * 8,
            ks + (size_t)gbase * 8);
    }
#pragma unroll
    for (int jj = 0; jj < 4; ++jj) {  // V^T tile: 128 rows x 8 granules
      int gbase = jj * 256 + wave * 64;
      int g = gbase + lane;
      int d = g >> 3, c = (g & 7) ^ (d & 7);
      GLL16(vt + ((size_t)(h * 128 + d)) * 4096 + kv0 + c * 8,
            vs + (size_t)gbase * 8);
    }
  };

  prefetch(kt_begin, 0);

  for (int it = 0; it < niter; ++it) {
    const int kt = kt_begin + it;
    const int kv0 = kt * 64;
    __syncthreads();  // drains this wave's GLL16s; gates buffer reuse
    if (it + 1 < niter) prefetch(kt + 1, (it + 1) & 1);
    const bf16* ksb = Ks + (it & 1) * (64 * 128);
    const bf16* vsb = Vs + (it & 1) * (128 * 64);

    if (kv0 > qminw + 31) continue;  // wave-uniform: tile entirely above diag

    // ---- S^T = K-tile * Q^T: kv-half chains acc0 (rows 0..31), acc1 (32..63)
    f32x16 acc0 = {}, acc1 = {};
    const int l15 = l31 & 15;
    __builtin_amdgcn_s_setprio(1);
#pragma unroll
    for (int f = 0; f < 8; ++f) {
      bf16x8 a0 = *(const bf16x8*)(
          ksb + (l31 * 16 + ((2 * f + hl) ^ l15)) * 8);
      bf16x8 a1 = *(const bf16x8*)(
          ksb + ((32 + l31) * 16 + ((2 * f + hl) ^ l15)) * 8);
      acc0 = __builtin_amdgcn_mfma_f32_32x32x16_bf16(a0, qf[f], acc0, 0, 0, 0);
      acc1 = __builtin_amdgcn_mfma_f32_32x32x16_bf16(a1, qf[f], acc1, 0, 0, 0);
    }
    __builtin_amdgcn_s_setprio(0);

    // ---- exp + causal mask (C row = (r&3)+8*(r>>2)+4*hl); mask only near diag
    const bool needmask = (kv0 + 63 > qminw);
    float rsp[4] = {0.f, 0.f, 0.f, 0.f};
    if (needmask) {
#pragma unroll
      for (int rr = 0; rr < 16; ++rr) {
        int kvl = (rr & 3) + 8 * (rr >> 2) + 4 * hl;
        float v0 = __expf(acc0[rr]);
        float v1 = __expf(acc1[rr]);
        if (kv0 + kvl > qg) v0 = 0.0f;
        if (kv0 + 32 + kvl > qg) v1 = 0.0f;
        acc0[rr] = v0; acc1[rr] = v1;
        rsp[rr & 3] += v0 + v1;
      }
    } else {
#pragma unroll
      for (int rr = 0; rr < 16; ++rr) {
        float v0 = __expf(acc0[rr]);
        float v1 = __expf(acc1[rr]);
        acc0[rr] = v0; acc1[rr] = v1;
        rsp[rr & 3] += v0 + v1;
      }
    }
    rs += (rsp[0] + rsp[1]) + (rsp[2] + rsp[3]);

    // pack kv-pairs: pkX[g] = (kv base(g)+4hl, +1), base(g)=8*(g>>1)+2*(g&1)
    int pk0[8], pk1[8];
#pragma unroll
    for (int g = 0; g < 8; ++g) {
      bf16x2 t0, t1;
      t0[0] = (bf16)acc0[2 * g]; t0[1] = (bf16)acc0[2 * g + 1];
      t1[0] = (bf16)acc1[2 * g]; t1[1] = (bf16)acc1[2 * g + 1];
      pk0[g] = __builtin_bit_cast(int, t0);
      pk1[g] = __builtin_bit_cast(int, t1);
    }

    // ---- in-register transpose to PV B-frags; chunk cc covers kv [cc*16,+16)
    bf16x8 pf[4];
#if __has_builtin(__builtin_amdgcn_permlane32_swap)
#pragma unroll
    for (int cc = 0; cc < 4; ++cc) {
      int s0 = (cc < 2) ? pk0[(cc & 1) * 4 + 0] : pk1[(cc & 1) * 4 + 0];
      int s1 = (cc < 2) ? pk0[(cc & 1) * 4 + 1] : pk1[(cc & 1) * 4 + 1];
      int s2 = (cc < 2) ? pk0[(cc & 1) * 4 + 2] : pk1[(cc & 1) * 4 + 2];
      int s3 = (cc < 2) ? pk0[(cc & 1) * 4 + 3] : pk1[(cc & 1) * 4 + 3];
      i32x2 r02 = __builtin_amdgcn_permlane32_swap(s0, s2, false, false);
      i32x2 r13 = __builtin_amdgcn_permlane32_swap(s1, s3, false, false);
      i32x4 dv;
      dv[0] = r02[0];  // t=0: src half 0
      dv[1] = r13[0];  // t=1: src half 0
      dv[2] = r02[1];  // t=2: src half 1
      dv[3] = r13[1];  // t=3: src half 1
      pf[cc] = __builtin_bit_cast(bf16x8, dv);
    }
#else
#pragma unroll
    for (int cc = 0; cc < 4; ++cc) {
      int s0 = (cc < 2) ? pk0[(cc & 1) * 4 + 0] : pk1[(cc & 1) * 4 + 0];
      int s1 = (cc < 2) ? pk0[(cc & 1) * 4 + 1] : pk1[(cc & 1) * 4 + 1];
      int s2 = (cc < 2) ? pk0[(cc & 1) * 4 + 2] : pk1[(cc & 1) * 4 + 2];
      int s3 = (cc < 2) ? pk0[(cc & 1) * 4 + 3] : pk1[(cc & 1) * 4 + 3];
      int sh0 = __shfl_xor(s0, 32, 64);
      int sh1 = __shfl_xor(s1, 32, 64);
      int sh2 = __shfl_xor(s2, 32, 64);
      int sh3 = __shfl_xor(s3, 32, 64);
      int own0 = hl ? s2 : s0;
      int own1 = hl ? s3 : s1;
      int par0 = hl ? sh2 : sh0;
      int par1 = hl ? sh3 : sh1;
      i32x4 dv;
      dv[0] = hl ? par0 : own0;
      dv[1] = hl ? par1 : own1;
      dv[2] = hl ? own0 : par0;
      dv[3] = hl ? own1 : par1;
      pf[cc] = __builtin_bit_cast(bf16x8, dv);
    }
#endif

    // ---- O^T[d][q] += V^T-tile * P^T; V kv-granule = 2*cc + hl
    __builtin_amdgcn_s_setprio(1);
#pragma unroll
    for (int dt = 0; dt < 4; ++dt) {
      int vrow = dt * 32 + l31;
#pragma unroll
      for (int cc = 0; cc < 4; ++cc) {
        bf16x8 a = *(const bf16x8*)(
            vsb + (vrow * 8 + ((2 * cc + hl) ^ (vrow & 7))) * 8);
        acc_o[dt] =
            __builtin_amdgcn_mfma_f32_32x32x16_bf16(a, pf[cc], acc_o[dt], 0, 0, 0);
      }
    }
    __builtin_amdgcn_s_setprio(0);
  }

  // ---- epilogue: each wave owns q rows [wave*32, +32) — direct float4 stores
  rs += __shfl_xor(rs, 32, 64);
  if (hl == 0) ls[pidx * 128 + wave * 32 + l31] = rs;
  float* opb = Op + (size_t)pidx * 16384 + (size_t)(wave * 32 + l31) * 128;
#pragma unroll
  for (int dt = 0; dt < 4; ++dt)
#pragma unroll
    for (int rg = 0; rg < 4; ++rg) {
      float4 o;
      o.x = acc_o[dt][rg * 4 + 0];
      o.y = acc_o[dt][rg * 4 + 1];
      o.z = acc_o[dt][rg * 4 + 2];
      o.w = acc_o[dt][rg * 4 + 3];
      int d0 = dt * 32 + 4 * hl + 8 * rg;
      *(float4*)(opb + d0) = o;
    }
}

// ---------------------------------------------------------------- combine halves
// y[t][h*128+d] = (Op[h,qt,0] + Op[h,qt,1]) / (l0 + l1), bf16. qt tiles of 128.
__global__ __launch_bounds__(256) void attn_combine(
    const float* __restrict__ Op, const float* __restrict__ ls,
    bf16* __restrict__ y) {
  int gid = blockIdx.x * 256 + threadIdx.x;  // one float4 of output each
  int t = gid >> 8;
  int c4 = gid & 255;
  int qt = t >> 7, ql = t & 127;
  int h = c4 >> 5;
  int d = (c4 & 31) * 4;
  int pb = (h * 32 + qt) * 2;
  const float4 o0 = *(const float4*)(Op + (size_t)pb * 16384 + ql * 128 + d);
  const float4 o1 =
      *(const float4*)(Op + (size_t)(pb + 1) * 16384 + ql * 128 + d);
  float inv = 1.0f / (ls[pb * 128 + ql] + ls[(pb + 1) * 128 + ql]);
  bf16x4 o;
  o[0] = (bf16)((o0.x + o1.x) * inv);
  o[1] = (bf16)((o0.y + o1.y) * inv);
  o[2] = (bf16)((o0.z + o1.z) * inv);
  o[3] = (bf16)((o0.w + o1.w) * inv);
  *(bf16x4*)(y + (size_t)t * 1024 + h * 128 + d) = o;
}

// ---------------------------------------------------------------- launch
extern "C" void kernel_launch(void* const* d_in, const int* in_sizes, int n_in,
                              void* d_out, int out_size, void* d_ws,
                              size_t ws_size, hipStream_t stream) {
  const float* x       = (const float*)d_in[0];  // [1,4096,1024]
  const float* ve      = (const float*)d_in[1];  // [1,4096,1024]
  const float* qkv_w   = (const float*)d_in[2];  // [3,1024,1024]
  const float* lambdas = (const float*)d_in[3];  // [2]
  const float* c_proj  = (const float*)d_in[4];  // [1024,1024]
  float* out = (float*)d_out;                    // [1,4096,1024] fp32

  char* ws = (char*)d_ws;
  bf16* xbf   = (bf16*)ws;                    // 8 MiB  (dead after gemm_qkv)
  bf16* wqkv  = (bf16*)(ws + 8388608);        // 6 MiB  (dead after gemm_qkv)
  // flash partials ALIAS the dead prefix (stream-ordered):
  float* Op  = (float*)ws;                    // 32 MiB  [512][128][128] f32
  float* lsw = (float*)(ws + 33554432);       // 256 KiB [512][128] f32
  bf16* wproj = (bf16*)(ws + 33816576);       // 2 MiB
  bf16* qn    = (bf16*)(ws + 35913728);       // 8 MiB
  bf16* kn    = (bf16*)(ws + 44302336);       // 8 MiB
  bf16* vt    = (bf16*)(ws + 52690944);       // 8 MiB  [H][128][T]
  bf16* yb    = (bf16*)(ws + 61079552);       // 8 MiB

  cast3_f32_bf16<<<2048, 256, 0, stream>>>(x, xbf, 4194304 / 4, qkv_w, wqkv,
                                           3145728 / 4, c_proj, wproj,
                                           1048576 / 4);

  gemm_qkv<<<dim3(24, 32), 256, 0, stream>>>(xbf, wqkv, ve, lambdas, qn, kn,
                                             vt);

  flash_attn<<<512, 256, 0, stream>>>(qn, kn, vt, Op, lsw);
  attn_combine<<<4096, 256, 0, stream>>>(Op, lsw, yb);

  gemm_bt<1024, 1024, 64, float><<<dim3(8, 64), 256, 0, stream>>>(yb, wproj,
                                                                  out);
}

// Round 12
// 210.443 us; speedup vs baseline: 1.6855x; 1.0243x over previous
//
#include <hip/hip_runtime.h>

typedef __bf16 bf16;
typedef __bf16 bf16x8 __attribute__((ext_vector_type(8)));
typedef __bf16 bf16x4 __attribute__((ext_vector_type(4)));
typedef __bf16 bf16x2 __attribute__((ext_vector_type(2)));
typedef float f32x4 __attribute__((ext_vector_type(4)));
typedef float f32x16 __attribute__((ext_vector_type(16)));
typedef int i32x4 __attribute__((ext_vector_type(4)));
typedef int i32x2 __attribute__((ext_vector_type(2)));

#define GLL16(gp, lp)                                                          \
  __builtin_amdgcn_global_load_lds(                                            \
      (const __attribute__((address_space(1))) unsigned int*)(gp),             \
      (__attribute__((address_space(3))) unsigned int*)(lp), 16, 0, 0)

// ------------------------------------------------------- fused fp32->bf16 casts
__global__ __launch_bounds__(256) void cast3_f32_bf16(
    const float* __restrict__ a, bf16* __restrict__ oa, int na4,
    const float* __restrict__ b, bf16* __restrict__ ob, int nb4,
    const float* __restrict__ c, bf16* __restrict__ oc, int nc4) {
  int i = blockIdx.x * blockDim.x + threadIdx.x;
  int stride = gridDim.x * blockDim.x;
  int total = na4 + nb4 + nc4;
  for (; i < total; i += stride) {
    const float4* src;
    bf16x4* dst;
    int j = i;
    if (j < na4) {
      src = (const float4*)a + j; dst = (bf16x4*)oa + j;
    } else if ((j -= na4) < nb4) {
      src = (const float4*)b + j; dst = (bf16x4*)ob + j;
    } else {
      j -= nb4;
      src = (const float4*)c + j; dst = (bf16x4*)oc + j;
    }
    float4 v = *src;
    bf16x4 o;
    o[0] = (bf16)v.x; o[1] = (bf16)v.y; o[2] = (bf16)v.z; o[3] = (bf16)v.w;
    *dst = o;
  }
}

// ---------------------------------------------------------------- GEMM C = A * B^T
// Round 22: single-barrier GLL16 double-buffer (proven in gemm_qkv, round 21).
// Stage tile t+1 after the barrier, compute tile t concurrently. Proj GEMM.
template <int K, int LDC, int BM, typename CT>
__global__ __launch_bounds__(256) void gemm_bt(
    const bf16* __restrict__ A, const bf16* __restrict__ B,
    CT* __restrict__ C) {
  constexpr int ASZ = BM * 64;          // elems per A buffer
  constexpr int BUF = ASZ + 128 * 64;   // elems per (A,B) buffer pair
  __shared__ __align__(16) bf16 smem[2 * BUF];
  const int tid  = threadIdx.x;
  const int lane = tid & 63;
  const int wave = tid >> 6;
  const int ln15 = lane & 15, quad = lane >> 4;
  const int wm = wave >> 1, wn = wave & 1;
  const int m0 = blockIdx.y * BM, n0 = blockIdx.x * 128;
  constexpr int MI = BM / 32;
  constexpr int NKT = K / 64;

  f32x4 acc[MI][4] = {};

  auto prefetch = [&](int kt, int buf) {
    const int k0 = kt * 64;
    bf16* As = smem + buf * BUF;
    bf16* Bs = As + ASZ;
#pragma unroll
    for (int j = 0; j < BM / 32; ++j) {
      int gbase = j * 256 + wave * 64;
      int g = gbase + lane;
      int r = g >> 3, c = (g & 7) ^ (r & 7);
      GLL16(A + (size_t)(m0 + r) * K + k0 + c * 8, As + (size_t)gbase * 8);
    }
#pragma unroll
    for (int j = 0; j < 4; ++j) {
      int gbase = j * 256 + wave * 64;
      int g = gbase + lane;
      int r = g >> 3, c = (g & 7) ^ (r & 7);
      GLL16(B + (size_t)(n0 + r) * K + k0 + c * 8, Bs + (size_t)gbase * 8);
    }
  };

  prefetch(0, 0);

  for (int kt = 0; kt < NKT; ++kt) {
    __syncthreads();  // drains tile-kt GLL16s; gates buffer reuse
    if (kt + 1 < NKT) prefetch(kt + 1, (kt + 1) & 1);
    const bf16* As = smem + (kt & 1) * BUF;
    const bf16* Bs = As + ASZ;
#pragma unroll
    for (int kk = 0; kk < 2; ++kk) {
      bf16x8 af[MI], bfr[4];
#pragma unroll
      for (int mi = 0; mi < MI; ++mi) {
        int m = wm * (BM / 2) + mi * 16 + ln15;
        int cg = kk * 4 + quad;
        af[mi] = *(const bf16x8*)(As + (m * 8 + (cg ^ (m & 7))) * 8);
      }
#pragma unroll
      for (int ni = 0; ni < 4; ++ni) {
        int n = wn * 64 + ni * 16 + ln15;
        int cg = kk * 4 + quad;
        bfr[ni] = *(const bf16x8*)(Bs + (n * 8 + (cg ^ (n & 7))) * 8);
      }
#pragma unroll
      for (int mi = 0; mi < MI; ++mi)
#pragma unroll
        for (int ni = 0; ni < 4; ++ni)
          acc[mi][ni] = __builtin_amdgcn_mfma_f32_16x16x32_bf16(
              af[mi], bfr[ni], acc[mi][ni], 0, 0, 0);
    }
  }
#pragma unroll
  for (int mi = 0; mi < MI; ++mi)
#pragma unroll
    for (int ni = 0; ni < 4; ++ni)
#pragma unroll
      for (int r = 0; r < 4; ++r) {
        int row = m0 + wm * (BM / 2) + mi * 16 + quad * 4 + r;
        int col = n0 + wn * 64 + ni * 16 + ln15;
        C[(size_t)row * LDC + col] = (CT)acc[mi][ni][r];
      }
}

// ----------------------------------------- qkv GEMM with FUSED qkv epilogue
// Round-21 proven: single-barrier GLL16 dbuf K-loop + round-9 epilogue
// VERBATIM (per-row sincos; the incremental-rotation variant failed
// correctness by drift — do not reintroduce).
__global__ __launch_bounds__(256) void gemm_qkv(
    const bf16* __restrict__ A, const bf16* __restrict__ B,
    const float* __restrict__ ve, const float* __restrict__ lmb,
    bf16* __restrict__ qn, bf16* __restrict__ kn, bf16* __restrict__ vt) {
  __shared__ __align__(16) bf16 smem[2 * 16384];  // 64 KB: 2 x (As 16K + Bs 16K)
  const int tid  = threadIdx.x;
  const int lane = tid & 63;
  const int wave = tid >> 6;
  const int ln15 = lane & 15, quad = lane >> 4;
  const int wm = wave >> 1, wn = wave & 1;
  const int m0 = blockIdx.y * 128, n0 = blockIdx.x * 128;

  f32x4 acc[4][4] = {};

  auto prefetch = [&](int kt, int buf) {
    const int k0 = kt * 64;
    bf16* As = smem + buf * 16384;
    bf16* Bs = As + 8192;
#pragma unroll
    for (int j = 0; j < 4; ++j) {
      int gbase = j * 256 + wave * 64;
      int g = gbase + lane;
      int r = g >> 3, c = (g & 7) ^ (r & 7);
      GLL16(A + (size_t)(m0 + r) * 1024 + k0 + c * 8, As + (size_t)gbase * 8);
    }
#pragma unroll
    for (int j = 0; j < 4; ++j) {
      int gbase = j * 256 + wave * 64;
      int g = gbase + lane;
      int r = g >> 3, c = (g & 7) ^ (r & 7);
      GLL16(B + (size_t)(n0 + r) * 1024 + k0 + c * 8, Bs + (size_t)gbase * 8);
    }
  };

  prefetch(0, 0);

  for (int kt = 0; kt < 16; ++kt) {
    __syncthreads();  // drains tile-kt GLL16s; gates buffer reuse
    if (kt + 1 < 16) prefetch(kt + 1, (kt + 1) & 1);
    const bf16* As = smem + (kt & 1) * 16384;
    const bf16* Bs = As + 8192;
#pragma unroll
    for (int kk = 0; kk < 2; ++kk) {
      bf16x8 af[4], bfr[4];
#pragma unroll
      for (int mi = 0; mi < 4; ++mi) {
        int m = wm * 64 + mi * 16 + ln15;
        int cg = kk * 4 + quad;
        af[mi] = *(const bf16x8*)(As + (m * 8 + (cg ^ (m & 7))) * 8);
      }
#pragma unroll
      for (int ni = 0; ni < 4; ++ni) {
        int n = wn * 64 + ni * 16 + ln15;
        int cg = kk * 4 + quad;
        bfr[ni] = *(const bf16x8*)(Bs + (n * 8 + (cg ^ (n & 7))) * 8);
      }
#pragma unroll
      for (int mi = 0; mi < 4; ++mi)
#pragma unroll
        for (int ni = 0; ni < 4; ++ni)
          acc[mi][ni] = __builtin_amdgcn_mfma_f32_16x16x32_bf16(
              af[mi], bfr[ni], acc[mi][ni], 0, 0, 0);
    }
  }

  // ---- fused epilogue: spill C-tile to LDS (staging buffers are dead)
  __syncthreads();
  bf16* tile = smem;  // [128][130] bf16 = 33.3 KB
#pragma unroll
  for (int mi = 0; mi < 4; ++mi)
#pragma unroll
    for (int ni = 0; ni < 4; ++ni)
#pragma unroll
      for (int r = 0; r < 4; ++r) {
        int row = wm * 64 + mi * 16 + quad * 4 + r;
        int col = wn * 64 + ni * 16 + ln15;
        tile[row * 130 + col] = (bf16)acc[mi][ni][r];
      }
  __syncthreads();

  const int ck = n0 >> 10;        // 0=q, 1=k, 2=v
  const int h  = (n0 >> 7) & 7;

  if (ck < 2) {
    // rms + rotary; each wave owns 32 rows, all 64 lanes per row. (round-9)
    const int j = lane;
    bf16* outb = (ck == 0 ? qn : kn);
    float ang = 0.f;
    if (j < 32) ang = exp2f((float)j * (-10.0f / 31.0f));
    for (int i = 0; i < 32; ++i) {
      int row = wave * 32 + i;
      int t = m0 + row;
      float x1 = (float)tile[row * 130 + j];
      float x2 = (float)tile[row * 130 + j + 64];
      float ss = x1 * x1 + x2 * x2;
#pragma unroll
      for (int m = 1; m < 64; m <<= 1) ss += __shfl_xor(ss, m, 64);
      float rinv = rsqrtf(ss * (1.0f / 128.0f) + 1.1920929e-7f);
      if (ck == 0) rinv *= 0.12f;  // fold ATTN_SCALE into q
      float c = 1.0f, s = 0.0f;
      if (j < 32) __sincosf((float)t * ang, &s, &c);
      float y1 = (x1 * c + x2 * s) * rinv;
      float y2 = (x2 * c - x1 * s) * rinv;
      bf16* orow = outb + (size_t)t * 1024 + h * 128;
      orow[j] = (bf16)y1;
      orow[j + 64] = (bf16)y2;
    }
  } else {
    // v: lambda-mix with ve (t-major, coalesced), then transposed write to vt
    float l0 = lmb[0], l1 = lmb[1];
    for (int c = 0; c < 32; ++c) {
      int idx = c * 512 + tid * 2;
      int d = idx & 127, tl = idx >> 7;
      int t = m0 + tl;
      bf16x2 vp = *(bf16x2*)(tile + tl * 130 + d);
      float2 vev = *(const float2*)(ve + (size_t)t * 1024 + h * 128 + d);
      bf16x2 o;
      o[0] = (bf16)(l0 * (float)vp[0] + l1 * vev.x);
      o[1] = (bf16)(l0 * (float)vp[1] + l1 * vev.y);
      *(bf16x2*)(tile + tl * 130 + d) = o;
    }
    __syncthreads();
    for (int c = 0; c < 32; ++c) {
      int idx = c * 512 + tid * 2;
      int tl = idx & 127, d = idx >> 7;  // two consecutive t, same d
      bf16x2 o;
      o[0] = tile[tl * 130 + d];
      o[1] = tile[(tl + 1) * 130 + d];
      *(bf16x2*)(vt + ((size_t)(h * 128 + d)) * 4096 + m0 + tl) = o;
    }
  }
}

// ---------------------------------------------------------------- flash attention
// Round 13 core (proven 57.5 us over 4 reruns): QBLK 128, 4 waves x 32 q-rows,
// full 64-kv tile per iter, single-barrier GLL16-dbuf pipeline, grid 512
// (2 blocks/CU; cross-block overlap hides barrier drains). DO NOT MODIFY:
// chunked-LPT (r14), fused-combine+fence (r16), 8-wave/1-per-CU (r18) all lost.
__global__ __launch_bounds__(256, 2) void flash_attn(
    const bf16* __restrict__ qn, const bf16* __restrict__ kn,
    const bf16* __restrict__ vt, float* __restrict__ Op,
    float* __restrict__ ls) {
  const int id = blockIdx.x;  // 0..511
  const int qt = (id < 256) ? (31 - (id >> 4)) : ((id - 256) >> 4);
  const int sub = id & 15;
  const int h = sub >> 1;
  const int half = sub & 1;
  const int tid = threadIdx.x;
  const int wave = tid >> 6, lane = tid & 63;
  const int l31 = lane & 31, hl = lane >> 5;

  __shared__ __align__(16) bf16 smem[4 * 64 * 128];  // 64 KB: Ks(2x16K)+Vs(2x16K)
  bf16* Ks = smem;                  // [buf][kv][16 gran] ^(kv&15)
  bf16* Vs = smem + 2 * 64 * 128;   // [buf][d][8 gran]  ^(d&7)

  const int nkv = 2 * (qt + 1);
  const int half0 = qt + 1;
  const int kt_begin = half ? half0 : 0;
  const int kt_end = half ? nkv : half0;
  const int niter = kt_end - kt_begin;  // = qt+1 >= 1
  const int pidx = (h * 32 + qt) * 2 + half;

  const int qminw = qt * 128 + wave * 32;  // this wave's lowest q row
  const int qg = qminw + l31;              // this lane's q (B n-dim / C col)

  // Q B-frags (B[k=d][n=q], k=(lane>>5)*8+j): 8 frags cover d=0..127.
  bf16x8 qf[8];
  {
    const bf16* qb = qn + (size_t)qg * 1024 + h * 128 + hl * 8;
#pragma unroll
    for (int f = 0; f < 8; ++f) qf[f] = *(const bf16x8*)(qb + f * 16);
  }

  f32x16 acc_o[4] = {};  // O^T[d=dt*32+..][q 32] for this wave
  float rs = 0.0f;

  auto prefetch = [&](int kt, int buf) {
    const int kv0 = kt * 64;
    bf16* ks = Ks + buf * (64 * 128);
    bf16* vs = Vs + buf * (128 * 64);
#pragma unroll
    for (int jj = 0; jj < 4; ++jj) {  // K tile: 64 rows x 16 granules
      int gbase = jj * 256 + wave * 64;
      int g = gbase + lane;
      int r = g >> 4, c = (g & 15) ^ (r & 15);
      GLL16(kn + (size_t)(kv0 + r) * 1024 + h * 128 + c * 8,
            ks + (size_t)gbase * 8);
    }
#pragma unroll
    for (int jj = 0; jj < 4; ++jj) {  // V^T tile: 128 rows x 8 granules
      int gbase = jj * 256 + wave * 64;
      int g = gbase + lane;
      int d = g >> 3, c = (g & 7) ^ (d & 7);
      GLL16(vt + ((size_t)(h * 128 + d)) * 4096 + kv0 + c * 8,
            vs + (size_t)gbase * 8);
    }
  };

  prefetch(kt_begin, 0);

  for (int it = 0; it < niter; ++it) {
    const int kt = kt_begin + it;
    const int kv0 = kt * 64;
    __syncthreads();  // drains this wave's GLL16s; gates buffer reuse
    if (it + 1 < niter) prefetch(kt + 1, (it + 1) & 1);
    const bf16* ksb = Ks + (it & 1) * (64 * 128);
    const bf16* vsb = Vs + (it & 1) * (128 * 64);

    if (kv0 > qminw + 31) continue;  // wave-uniform: tile entirely above diag

    // ---- S^T = K-tile * Q^T: kv-half chains acc0 (rows 0..31), acc1 (32..63)
    f32x16 acc0 = {}, acc1 = {};
    const int l15 = l31 & 15;
    __builtin_amdgcn_s_setprio(1);
#pragma unroll
    for (int f = 0; f < 8; ++f) {
      bf16x8 a0 = *(const bf16x8*)(
          ksb + (l31 * 16 + ((2 * f + hl) ^ l15)) * 8);
      bf16x8 a1 = *(const bf16x8*)(
          ksb + ((32 + l31) * 16 + ((2 * f + hl) ^ l15)) * 8);
      acc0 = __builtin_amdgcn_mfma_f32_32x32x16_bf16(a0, qf[f], acc0, 0, 0, 0);
      acc1 = __builtin_amdgcn_mfma_f32_32x32x16_bf16(a1, qf[f], acc1, 0, 0, 0);
    }
    __builtin_amdgcn_s_setprio(0);

    // ---- exp + causal mask (C row = (r&3)+8*(r>>2)+4*hl); mask only near diag
    const bool needmask = (kv0 + 63 > qminw);
    float rsp[4] = {0.f, 0.f, 0.f, 0.f};
    if (needmask) {
#pragma unroll
      for (int rr = 0; rr < 16; ++rr) {
        int kvl = (rr & 3) + 8 * (rr >> 2) + 4 * hl;
        float v0 = __expf(acc0[rr]);
        float v1 = __expf(acc1[rr]);
        if (kv0 + kvl > qg) v0 = 0.0f;
        if (kv0 + 32 + kvl > qg) v1 = 0.0f;
        acc0[rr] = v0; acc1[rr] = v1;
        rsp[rr & 3] += v0 + v1;
      }
    } else {
#pragma unroll
      for (int rr = 0; rr < 16; ++rr) {
        float v0 = __expf(acc0[rr]);
        float v1 = __expf(acc1[rr]);
        acc0[rr] = v0; acc1[rr] = v1;
        rsp[rr & 3] += v0 + v1;
      }
    }
    rs += (rsp[0] + rsp[1]) + (rsp[2] + rsp[3]);

    // pack kv-pairs: pkX[g] = (kv base(g)+4hl, +1), base(g)=8*(g>>1)+2*(g&1)
    int pk0[8], pk1[8];
#pragma unroll
    for (int g = 0; g < 8; ++g) {
      bf16x2 t0, t1;
      t0[0] = (bf16)acc0[2 * g]; t0[1] = (bf16)acc0[2 * g + 1];
      t1[0] = (bf16)acc1[2 * g]; t1[1] = (bf16)acc1[2 * g + 1];
      pk0[g] = __builtin_bit_cast(int, t0);
      pk1[g] = __builtin_bit_cast(int, t1);
    }

    // ---- in-register transpose to PV B-frags; chunk cc covers kv [cc*16,+16)
    bf16x8 pf[4];
#if __has_builtin(__builtin_amdgcn_permlane32_swap)
#pragma unroll
    for (int cc = 0; cc < 4; ++cc) {
      int s0 = (cc < 2) ? pk0[(cc & 1) * 4 + 0] : pk1[(cc & 1) * 4 + 0];
      int s1 = (cc < 2) ? pk0[(cc & 1) * 4 + 1] : pk1[(cc & 1) * 4 + 1];
      int s2 = (cc < 2) ? pk0[(cc & 1) * 4 + 2] : pk1[(cc & 1) * 4 + 2];
      int s3 = (cc < 2) ? pk0[(cc & 1) * 4 + 3] : pk1[(cc & 1) * 4 + 3];
      i32x2 r02 = __builtin_amdgcn_permlane32_swap(s0, s2, false, false);
      i32x2 r13 = __builtin_amdgcn_permlane32_swap(s1, s3, false, false);
      i32x4 dv;
      dv[0] = r02[0];  // t=0: src half 0
      dv[1] = r13[0];  // t=1: src half 0
      dv[2] = r02[1];  // t=2: src half 1
      dv[3] = r13[1];  // t=3: src half 1
      pf[cc] = __builtin_bit_cast(bf16x8, dv);
    }
#else
#pragma unroll
    for (int cc = 0; cc < 4; ++cc) {
      int s0 = (cc < 2) ? pk0[(cc & 1) * 4 + 0] : pk1[(cc & 1) * 4 + 0];
      int s1 = (cc < 2) ? pk0[(cc & 1) * 4 + 1] : pk1[(cc & 1) * 4 + 1];
      int s2 = (cc < 2) ? pk0[(cc & 1) * 4 + 2] : pk1[(cc & 1) * 4 + 2];
      int s3 = (cc < 2) ? pk0[(cc & 1) * 4 + 3] : pk1[(cc & 1) * 4 + 3];
      int sh0 = __shfl_xor(s0, 32, 64);
      int sh1 = __shfl_xor(s1, 32, 64);
      int sh2 = __shfl_xor(s2, 32, 64);
      int sh3 = __shfl_xor(s3, 32, 64);
      int own0 = hl ? s2 : s0;
      int own1 = hl ? s3 : s1;
      int par0 = hl ? sh2 : sh0;
      int par1 = hl ? sh3 : sh1;
      i32x4 dv;
      dv[0] = hl ? par0 : own0;
      dv[1] = hl ? par1 : own1;
      dv[2] = hl ? own0 : par0;
      dv[3] = hl ? own1 : par1;
      pf[cc] = __builtin_bit_cast(bf16x8, dv);
    }
#endif

    // ---- O^T[d][q] += V^T-tile * P^T; V kv-granule = 2*cc + hl
    __builtin_amdgcn_s_setprio(1);
#pragma unroll
    for (int dt = 0; dt < 4; ++dt) {
      int vrow = dt * 32 + l31;
#pragma unroll
      for (int cc = 0; cc < 4; ++cc) {
        bf16x8 a = *(const bf16x8*)(
            vsb + (vrow * 8 + ((2 * cc + hl) ^ (vrow & 7))) * 8);
        acc_o[dt] =
            __builtin_amdgcn_mfma_f32_32x32x16_bf16(a, pf[cc], acc_o[dt], 0, 0, 0);
      }
    }
    __builtin_amdgcn_s_setprio(0);
  }

  // ---- epilogue: each wave owns q rows [wave*32, +32) — direct float4 stores
  rs += __shfl_xor(rs, 32, 64);
  if (hl == 0) ls[pidx * 128 + wave * 32 + l31] = rs;
  float* opb = Op + (size_t)pidx * 16384 + (size_t)(wave * 32 + l31) * 128;
#pragma unroll
  for (int dt = 0; dt < 4; ++dt)
#pragma unroll
    for (int rg = 0; rg < 4; ++rg) {
      float4 o;
      o.x = acc_o[dt][rg * 4 + 0];
      o.y = acc_o[dt][rg * 4 + 1];
      o.z = acc_o[dt][rg * 4 + 2];
      o.w = acc_o[dt][rg * 4 + 3];
      int d0 = dt * 32 + 4 * hl + 8 * rg;
      *(float4*)(opb + d0) = o;
    }
}

// ---------------------------------------------------------------- combine halves
// y[t][h*128+d] = (Op[h,qt,0] + Op[h,qt,1]) / (l0 + l1), bf16. qt tiles of 128.
__global__ __launch_bounds__(256) void attn_combine(
    const float* __restrict__ Op, const float* __restrict__ ls,
    bf16* __restrict__ y) {
  int gid = blockIdx.x * 256 + threadIdx.x;  // one float4 of output each
  int t = gid >> 8;
  int c4 = gid & 255;
  int qt = t >> 7, ql = t & 127;
  int h = c4 >> 5;
  int d = (c4 & 31) * 4;
  int pb = (h * 32 + qt) * 2;
  const float4 o0 = *(const float4*)(Op + (size_t)pb * 16384 + ql * 128 + d);
  const float4 o1 =
      *(const float4*)(Op + (size_t)(pb + 1) * 16384 + ql * 128 + d);
  float inv = 1.0f / (ls[pb * 128 + ql] + ls[(pb + 1) * 128 + ql]);
  bf16x4 o;
  o[0] = (bf16)((o0.x + o1.x) * inv);
  o[1] = (bf16)((o0.y + o1.y) * inv);
  o[2] = (bf16)((o0.z + o1.z) * inv);
  o[3] = (bf16)((o0.w + o1.w) * inv);
  *(bf16x4*)(y + (size_t)t * 1024 + h * 128 + d) = o;
}

// ---------------------------------------------------------------- launch
extern "C" void kernel_launch(void* const* d_in, const int* in_sizes, int n_in,
                              void* d_out, int out_size, void* d_ws,
                              size_t ws_size, hipStream_t stream) {
  const float* x       = (const float*)d_in[0];  // [1,4096,1024]
  const float* ve      = (const float*)d_in[1];  // [1,4096,1024]
  const float* qkv_w   = (const float*)d_in[2];  // [3,1024,1024]
  const float* lambdas = (const float*)d_in[3];  // [2]
  const float* c_proj  = (const float*)d_in[4];  // [1024,1024]
  float* out = (float*)d_out;                    // [1,4096,1024] fp32

  char* ws = (char*)d_ws;
  bf16* xbf   = (bf16*)ws;                    // 8 MiB  (dead after gemm_qkv)
  bf16* wqkv  = (bf16*)(ws + 8388608);        // 6 MiB  (dead after gemm_qkv)
  // flash partials ALIAS the dead prefix (stream-ordered):
  float* Op  = (float*)ws;                    // 32 MiB  [512][128][128] f32
  float* lsw = (float*)(ws + 33554432);       // 256 KiB [512][128] f32
  bf16* wproj = (bf16*)(ws + 33816576);       // 2 MiB
  bf16* qn    = (bf16*)(ws + 35913728);       // 8 MiB
  bf16* kn    = (bf16*)(ws + 44302336);       // 8 MiB
  bf16* vt    = (bf16*)(ws + 52690944);       // 8 MiB  [H][128][T]
  bf16* yb    = (bf16*)(ws + 61079552);       // 8 MiB

  cast3_f32_bf16<<<2048, 256, 0, stream>>>(x, xbf, 4194304 / 4, qkv_w, wqkv,
                                           3145728 / 4, c_proj, wproj,
                                           1048576 / 4);

  gemm_qkv<<<dim3(24, 32), 256, 0, stream>>>(xbf, wqkv, ve, lambdas, qn, kn,
                                             vt);

  flash_attn<<<512, 256, 0, stream>>>(qn, kn, vt, Op, lsw);
  attn_combine<<<4096, 256, 0, stream>>>(Op, lsw, yb);

  gemm_bt<1024, 1024, 64, float><<<dim3(8, 64), 256, 0, stream>>>(yb, wproj,
                                                                  out);
}